// Round 1
// baseline (6898.310 us; speedup 1.0000x reference)
//
#include <hip/hip_runtime.h>
#include <math.h>

#define NNODES 50000
#define NEDGES 100000
#define HID 128

// ---------------------------------------------------------------------------
// degrees: dv[r] += val, de[c] += val  (HW f32 atomics)
// ---------------------------------------------------------------------------
__global__ __launch_bounds__(256) void deg_kernel(
    const int* __restrict__ rows, const int* __restrict__ cols,
    const float* __restrict__ vals, float* __restrict__ dv,
    float* __restrict__ de, int nnz) {
  int i = blockIdx.x * 256 + threadIdx.x;
  if (i >= nnz) return;
  float v = vals[i];
  unsafeAtomicAdd(&dv[rows[i]], v);
  unsafeAtomicAdd(&de[cols[i]], v);
}

// dv <- 1/sqrt(max(dv,1e-6)); de <- 1/max(de,1e-6)
__global__ __launch_bounds__(256) void inv_kernel(float* __restrict__ dv,
                                                  float* __restrict__ de) {
  int i = blockIdx.x * 256 + threadIdx.x;
  if (i < NNODES) {
    dv[i] = 1.0f / sqrtf(fmaxf(dv[i], 1e-6f));
  } else if (i < NNODES + NEDGES) {
    int j = i - NNODES;
    de[j] = 1.0f / fmaxf(de[j], 1e-6f);
  }
}

// ---------------------------------------------------------------------------
// Ye[c,:] += vals[i] * dvis[r] * X[r,:]        (32 lanes/nnz, float4 lanes)
// ---------------------------------------------------------------------------
__global__ __launch_bounds__(256) void scatter_edge_kernel(
    const float* __restrict__ X, float* __restrict__ Ye,
    const int* __restrict__ rows, const int* __restrict__ cols,
    const float* __restrict__ vals, const float* __restrict__ dvis, int nnz) {
  int g = (blockIdx.x * 256 + threadIdx.x) >> 5;
  int lane = threadIdx.x & 31;
  if (g >= nnz) return;
  int r = rows[g];
  int c = cols[g];
  float s = vals[g] * dvis[r];
  float4 x = reinterpret_cast<const float4*>(X)[(size_t)r * 32 + lane];
  float* dst = Ye + (size_t)c * HID + lane * 4;
  unsafeAtomicAdd(dst + 0, s * x.x);
  unsafeAtomicAdd(dst + 1, s * x.y);
  unsafeAtomicAdd(dst + 2, s * x.z);
  unsafeAtomicAdd(dst + 3, s * x.w);
}

// ---------------------------------------------------------------------------
// Yn[r,:] += vals[i] * dein[c] * Ye[c,:]
// ---------------------------------------------------------------------------
__global__ __launch_bounds__(256) void scatter_node_kernel(
    const float* __restrict__ Ye, float* __restrict__ Yn,
    const int* __restrict__ rows, const int* __restrict__ cols,
    const float* __restrict__ vals, const float* __restrict__ dein, int nnz) {
  int g = (blockIdx.x * 256 + threadIdx.x) >> 5;
  int lane = threadIdx.x & 31;
  if (g >= nnz) return;
  int r = rows[g];
  int c = cols[g];
  float s = vals[g] * dein[c];
  float4 y = reinterpret_cast<const float4*>(Ye)[(size_t)c * 32 + lane];
  float* dst = Yn + (size_t)r * HID + lane * 4;
  unsafeAtomicAdd(dst + 0, s * y.x);
  unsafeAtomicAdd(dst + 1, s * y.y);
  unsafeAtomicAdd(dst + 2, s * y.z);
  unsafeAtomicAdd(dst + 3, s * y.w);
}

// ---------------------------------------------------------------------------
// out[n,:] = act( dvis[n] * (Pn[n,:] @ W^T) )
// W row-major [128][128]; staged transposed in LDS (WT[k][j] = W[j][k]).
// Block: 256 thr = 8 groups of 32 lanes; group computes 2 rows/iter, 4 iters
// -> 64 rows per block. Lane computes 4 columns (j = lane*4..lane*4+3).
// ---------------------------------------------------------------------------
__global__ __launch_bounds__(256) void gemm_kernel(
    const float* __restrict__ Pn, const float* __restrict__ dvis,
    const float* __restrict__ W, float* __restrict__ out, int do_relu) {
  __shared__ float WT[HID * HID];  // 64 KB
  for (int idx = threadIdx.x; idx < HID * HID; idx += 256) {
    int j = idx >> 7;
    int k = idx & 127;
    WT[k * HID + j] = W[idx];
  }
  __syncthreads();

  int lane = threadIdx.x & 31;
  int grp = threadIdx.x >> 5;  // 0..7
  const float4* X4 = reinterpret_cast<const float4*>(Pn);
  const float4* WT4 = reinterpret_cast<const float4*>(WT);
  int base = blockIdx.x * 64;

  for (int it = 0; it < 4; ++it) {
    int r0 = base + it * 16 + grp * 2;
    int r1 = r0 + 1;
    int rr0 = r0 < NNODES ? r0 : NNODES - 1;
    int rr1 = r1 < NNODES ? r1 : NNODES - 1;
    float4 a0 = make_float4(0.f, 0.f, 0.f, 0.f);
    float4 a1 = make_float4(0.f, 0.f, 0.f, 0.f);
#pragma unroll 4
    for (int kk = 0; kk < 32; ++kk) {
      float4 x0 = X4[(size_t)rr0 * 32 + kk];
      float4 x1 = X4[(size_t)rr1 * 32 + kk];
      const float* x0p = reinterpret_cast<const float*>(&x0);
      const float* x1p = reinterpret_cast<const float*>(&x1);
#pragma unroll
      for (int q = 0; q < 4; ++q) {
        float4 w = WT4[(kk * 4 + q) * 32 + lane];
        a0.x += x0p[q] * w.x;
        a0.y += x0p[q] * w.y;
        a0.z += x0p[q] * w.z;
        a0.w += x0p[q] * w.w;
        a1.x += x1p[q] * w.x;
        a1.y += x1p[q] * w.y;
        a1.z += x1p[q] * w.z;
        a1.w += x1p[q] * w.w;
      }
    }
    if (r0 < NNODES) {
      float s = dvis[r0];
      float4 o = make_float4(s * a0.x, s * a0.y, s * a0.z, s * a0.w);
      if (do_relu) {
        o.x = fmaxf(o.x, 0.f); o.y = fmaxf(o.y, 0.f);
        o.z = fmaxf(o.z, 0.f); o.w = fmaxf(o.w, 0.f);
      }
      reinterpret_cast<float4*>(out)[(size_t)r0 * 32 + lane] = o;
    }
    if (r1 < NNODES) {
      float s = dvis[r1];
      float4 o = make_float4(s * a1.x, s * a1.y, s * a1.z, s * a1.w);
      if (do_relu) {
        o.x = fmaxf(o.x, 0.f); o.y = fmaxf(o.y, 0.f);
        o.z = fmaxf(o.z, 0.f); o.w = fmaxf(o.w, 0.f);
      }
      reinterpret_cast<float4*>(out)[(size_t)r1 * 32 + lane] = o;
    }
  }
}

// ---------------------------------------------------------------------------
extern "C" void kernel_launch(void* const* d_in, const int* in_sizes, int n_in,
                              void* d_out, int out_size, void* d_ws,
                              size_t ws_size, hipStream_t stream) {
  const int* rows = (const int*)d_in[0];
  const int* cols = (const int*)d_in[1];
  const float* vals = (const float*)d_in[2];
  const float* X0 = (const float*)d_in[3];
  const float* W0 = (const float*)d_in[4];
  const float* W1 = (const float*)d_in[5];
  const int nnz = in_sizes[0];
  float* out = (float*)d_out;

  // workspace layout (fp32):
  //   dv [NNODES] | de [NEDGES] | Ye [NEDGES*HID] | Pn [NNODES*HID]
  // X1 intermediate lives in d_out (overwritten by final GEMM).
  float* dv = (float*)d_ws;
  float* de = dv + NNODES;
  float* Ye = de + NEDGES;
  float* Pn = Ye + (size_t)NEDGES * HID;

  const int scat_blocks = (nnz + 7) / 8;
  const int gemm_blocks = (NNODES + 63) / 64;

  // degrees
  hipMemsetAsync(dv, 0, (size_t)(NNODES + NEDGES) * sizeof(float), stream);
  deg_kernel<<<(nnz + 255) / 256, 256, 0, stream>>>(rows, cols, vals, dv, de, nnz);
  inv_kernel<<<(NNODES + NEDGES + 255) / 256, 256, 0, stream>>>(dv, de);

  // ---- pass 1: X1 = relu((P @ X0) @ W0^T) -> stored in d_out ----
  hipMemsetAsync(Ye, 0, (size_t)NEDGES * HID * sizeof(float), stream);
  scatter_edge_kernel<<<scat_blocks, 256, 0, stream>>>(X0, Ye, rows, cols, vals, dv, nnz);
  hipMemsetAsync(Pn, 0, (size_t)NNODES * HID * sizeof(float), stream);
  scatter_node_kernel<<<scat_blocks, 256, 0, stream>>>(Ye, Pn, rows, cols, vals, de, nnz);
  gemm_kernel<<<gemm_blocks, 256, 0, stream>>>(Pn, dv, W0, out, 1);

  // ---- pass 2: Z = (P @ X1) @ W1^T -> d_out ----
  hipMemsetAsync(Ye, 0, (size_t)NEDGES * HID * sizeof(float), stream);
  scatter_edge_kernel<<<scat_blocks, 256, 0, stream>>>(out, Ye, rows, cols, vals, dv, nnz);
  hipMemsetAsync(Pn, 0, (size_t)NNODES * HID * sizeof(float), stream);
  scatter_node_kernel<<<scat_blocks, 256, 0, stream>>>(Ye, Pn, rows, cols, vals, de, nnz);
  gemm_kernel<<<gemm_blocks, 256, 0, stream>>>(Pn, dv, W1, out, 0);
}

// Round 2
// 965.549 us; speedup vs baseline: 7.1444x; 7.1444x over previous
//
#include <hip/hip_runtime.h>
#include <math.h>

#define NNODES 50000
#define NEDGES 100000
#define HID 128

// ===========================================================================
// Common small kernels
// ===========================================================================

// degrees + histogram: dv[r]+=v, de[c]+=v, e_cnt[c]++, n_cnt[r]++
__global__ __launch_bounds__(256) void deg_hist_kernel(
    const int* __restrict__ rows, const int* __restrict__ cols,
    const float* __restrict__ vals, float* __restrict__ dv,
    float* __restrict__ de, int* __restrict__ e_cnt, int* __restrict__ n_cnt,
    int nnz) {
  int i = blockIdx.x * 256 + threadIdx.x;
  if (i >= nnz) return;
  float v = vals[i];
  int r = rows[i], c = cols[i];
  unsafeAtomicAdd(&dv[r], v);
  unsafeAtomicAdd(&de[c], v);
  atomicAdd(&e_cnt[c], 1);
  atomicAdd(&n_cnt[r], 1);
}

// dv <- 1/sqrt(max(dv,1e-6)); de <- 1/max(de,1e-6)
__global__ __launch_bounds__(256) void inv_kernel(float* __restrict__ dv,
                                                  float* __restrict__ de) {
  int i = blockIdx.x * 256 + threadIdx.x;
  if (i < NNODES) {
    dv[i] = 1.0f / sqrtf(fmaxf(dv[i], 1e-6f));
  } else if (i < NNODES + NEDGES) {
    int j = i - NNODES;
    de[j] = 1.0f / fmaxf(de[j], 1e-6f);
  }
}

// single-block exclusive scan (in-place on data; copy to cur). n <= a few 100K.
__global__ __launch_bounds__(1024) void scan_excl_kernel(int* __restrict__ data,
                                                         int* __restrict__ cur,
                                                         int n) {
  __shared__ int sums[16];
  __shared__ int carry;
  int tid = threadIdx.x;
  int lane = tid & 63, wid = tid >> 6;
  if (tid == 0) carry = 0;
  __syncthreads();
  for (int base = 0; base < n; base += 1024) {
    int pos = base + tid;
    int x = (pos < n) ? data[pos] : 0;
    int incl = x;
#pragma unroll
    for (int d = 1; d < 64; d <<= 1) {
      int t = __shfl_up(incl, d, 64);
      if (lane >= d) incl += t;
    }
    if (lane == 63) sums[wid] = incl;
    __syncthreads();
    int prefix = carry;
    for (int k = 0; k < wid; ++k) prefix += sums[k];
    int excl = prefix + incl - x;
    if (pos < n) {
      data[pos] = excl;
      cur[pos] = excl;
    }
    int total = 0;
    for (int k = 0; k < 16; ++k) total += sums[k];
    __syncthreads();
    if (tid == 0) carry += total;
    __syncthreads();
  }
}

// scatter incidences into both sorted layouts, folding the degree scales:
//   edge list (grouped by col): e_idx[p]=row, e_w[p]=val*dvis[row]
//   node list (grouped by row): n_idx[q]=col, n_w[q]=val*dein[col]
__global__ __launch_bounds__(256) void build_kernel(
    const int* __restrict__ rows, const int* __restrict__ cols,
    const float* __restrict__ vals, const float* __restrict__ dvis,
    const float* __restrict__ dein, int* __restrict__ e_cur,
    int* __restrict__ n_cur, int* __restrict__ e_idx, float* __restrict__ e_w,
    int* __restrict__ n_idx, float* __restrict__ n_w, int nnz) {
  int i = blockIdx.x * 256 + threadIdx.x;
  if (i >= nnz) return;
  int r = rows[i], c = cols[i];
  float v = vals[i];
  int p = atomicAdd(&e_cur[c], 1);
  e_idx[p] = r;
  e_w[p] = v * dvis[r];
  int q = atomicAdd(&n_cur[r], 1);
  n_idx[q] = c;
  n_w[q] = v * dein[c];
}

// one wave64 per segment: dst[e,:] = sum_j w[j] * src[idx[j],:]
__global__ __launch_bounds__(256) void gather_kernel(
    const float* __restrict__ src, float* __restrict__ dst,
    const int* __restrict__ off, const int* __restrict__ idx,
    const float* __restrict__ w, int nseg) {
  int e = blockIdx.x * 4 + (threadIdx.x >> 6);
  int lane = threadIdx.x & 63;
  if (e >= nseg) return;
  int s = off[e], t = off[e + 1];
  const float2* S2 = reinterpret_cast<const float2*>(src);
  float2 acc = make_float2(0.f, 0.f);
  int j = s;
  for (; j + 1 < t; j += 2) {
    int r0 = idx[j], r1 = idx[j + 1];
    float w0 = w[j], w1 = w[j + 1];
    float2 x0 = S2[(size_t)r0 * 64 + lane];
    float2 x1 = S2[(size_t)r1 * 64 + lane];
    acc.x = fmaf(w0, x0.x, acc.x);
    acc.y = fmaf(w0, x0.y, acc.y);
    acc.x = fmaf(w1, x1.x, acc.x);
    acc.y = fmaf(w1, x1.y, acc.y);
  }
  if (j < t) {
    int r0 = idx[j];
    float w0 = w[j];
    float2 x0 = S2[(size_t)r0 * 64 + lane];
    acc.x = fmaf(w0, x0.x, acc.x);
    acc.y = fmaf(w0, x0.y, acc.y);
  }
  reinterpret_cast<float2*>(dst)[(size_t)e * 64 + lane] = acc;
}

// ===========================================================================
// GEMM: out[n,:] = act( dvis[n] * (Pn[n,:] @ W^T) )
// ===========================================================================
__global__ __launch_bounds__(256) void gemm_kernel(
    const float* __restrict__ Pn, const float* __restrict__ dvis,
    const float* __restrict__ W, float* __restrict__ out, int do_relu) {
  __shared__ float WT[HID * HID];  // 64 KB, WT[k][j] = W[j][k]
  for (int idx = threadIdx.x; idx < HID * HID; idx += 256) {
    int j = idx >> 7;
    int k = idx & 127;
    WT[k * HID + j] = W[idx];
  }
  __syncthreads();

  int lane = threadIdx.x & 31;
  int grp = threadIdx.x >> 5;  // 0..7
  const float4* X4 = reinterpret_cast<const float4*>(Pn);
  const float4* WT4 = reinterpret_cast<const float4*>(WT);
  int base = blockIdx.x * 64;

  for (int it = 0; it < 4; ++it) {
    int r0 = base + it * 16 + grp * 2;
    int r1 = r0 + 1;
    int rr0 = r0 < NNODES ? r0 : NNODES - 1;
    int rr1 = r1 < NNODES ? r1 : NNODES - 1;
    float4 a0 = make_float4(0.f, 0.f, 0.f, 0.f);
    float4 a1 = make_float4(0.f, 0.f, 0.f, 0.f);
#pragma unroll 4
    for (int kk = 0; kk < 32; ++kk) {
      float4 x0 = X4[(size_t)rr0 * 32 + kk];
      float4 x1 = X4[(size_t)rr1 * 32 + kk];
      const float* x0p = reinterpret_cast<const float*>(&x0);
      const float* x1p = reinterpret_cast<const float*>(&x1);
#pragma unroll
      for (int q = 0; q < 4; ++q) {
        float4 w = WT4[(kk * 4 + q) * 32 + lane];
        a0.x += x0p[q] * w.x; a0.y += x0p[q] * w.y;
        a0.z += x0p[q] * w.z; a0.w += x0p[q] * w.w;
        a1.x += x1p[q] * w.x; a1.y += x1p[q] * w.y;
        a1.z += x1p[q] * w.z; a1.w += x1p[q] * w.w;
      }
    }
    if (r0 < NNODES) {
      float s = dvis[r0];
      float4 o = make_float4(s * a0.x, s * a0.y, s * a0.z, s * a0.w);
      if (do_relu) {
        o.x = fmaxf(o.x, 0.f); o.y = fmaxf(o.y, 0.f);
        o.z = fmaxf(o.z, 0.f); o.w = fmaxf(o.w, 0.f);
      }
      reinterpret_cast<float4*>(out)[(size_t)r0 * 32 + lane] = o;
    }
    if (r1 < NNODES) {
      float s = dvis[r1];
      float4 o = make_float4(s * a1.x, s * a1.y, s * a1.z, s * a1.w);
      if (do_relu) {
        o.x = fmaxf(o.x, 0.f); o.y = fmaxf(o.y, 0.f);
        o.z = fmaxf(o.z, 0.f); o.w = fmaxf(o.w, 0.f);
      }
      reinterpret_cast<float4*>(out)[(size_t)r1 * 32 + lane] = o;
    }
  }
}

// ===========================================================================
// Fallback (R1 atomic-scatter path) kernels
// ===========================================================================
__global__ __launch_bounds__(256) void scatter_edge_kernel(
    const float* __restrict__ X, float* __restrict__ Ye,
    const int* __restrict__ rows, const int* __restrict__ cols,
    const float* __restrict__ vals, const float* __restrict__ dvis, int nnz) {
  int g = (blockIdx.x * 256 + threadIdx.x) >> 5;
  int lane = threadIdx.x & 31;
  if (g >= nnz) return;
  int r = rows[g];
  int c = cols[g];
  float s = vals[g] * dvis[r];
  float4 x = reinterpret_cast<const float4*>(X)[(size_t)r * 32 + lane];
  float* dst = Ye + (size_t)c * HID + lane * 4;
  unsafeAtomicAdd(dst + 0, s * x.x);
  unsafeAtomicAdd(dst + 1, s * x.y);
  unsafeAtomicAdd(dst + 2, s * x.z);
  unsafeAtomicAdd(dst + 3, s * x.w);
}

__global__ __launch_bounds__(256) void scatter_node_kernel(
    const float* __restrict__ Ye, float* __restrict__ Yn,
    const int* __restrict__ rows, const int* __restrict__ cols,
    const float* __restrict__ vals, const float* __restrict__ dein, int nnz) {
  int g = (blockIdx.x * 256 + threadIdx.x) >> 5;
  int lane = threadIdx.x & 31;
  if (g >= nnz) return;
  int r = rows[g];
  int c = cols[g];
  float s = vals[g] * dein[c];
  float4 y = reinterpret_cast<const float4*>(Ye)[(size_t)c * 32 + lane];
  float* dst = Yn + (size_t)r * HID + lane * 4;
  unsafeAtomicAdd(dst + 0, s * y.x);
  unsafeAtomicAdd(dst + 1, s * y.y);
  unsafeAtomicAdd(dst + 2, s * y.z);
  unsafeAtomicAdd(dst + 3, s * y.w);
}

// ===========================================================================
extern "C" void kernel_launch(void* const* d_in, const int* in_sizes, int n_in,
                              void* d_out, int out_size, void* d_ws,
                              size_t ws_size, hipStream_t stream) {
  const int* rows = (const int*)d_in[0];
  const int* cols = (const int*)d_in[1];
  const float* vals = (const float*)d_in[2];
  const float* X0 = (const float*)d_in[3];
  const float* W0 = (const float*)d_in[4];
  const float* W1 = (const float*)d_in[5];
  const int nnz = in_sizes[0];
  float* out = (float*)d_out;

  const int gemm_blocks = (NNODES + 63) / 64;

  // sorted-CSR workspace layout (all 4-byte elems):
  // dv[N] | de[E] | e_off[E+1] | n_off[N+1] | e_cur[E+1] | n_cur[N+1] |
  // e_idx[nnz] | e_w[nnz] | n_idx[nnz] | n_w[nnz] | Ye[E*HID] | Pn[N*HID]
  size_t elems = (size_t)NNODES + NEDGES + 2 * (NEDGES + 1) + 2 * (NNODES + 1) +
                 4 * (size_t)nnz + (size_t)NEDGES * HID + (size_t)NNODES * HID;
  size_t need = elems * 4;

  if (ws_size >= need) {
    float* dv = (float*)d_ws;
    float* de = dv + NNODES;
    int* e_off = (int*)(de + NEDGES);
    int* n_off = e_off + NEDGES + 1;
    int* e_cur = n_off + NNODES + 1;
    int* n_cur = e_cur + NEDGES + 1;
    int* e_idx = n_cur + NNODES + 1;
    float* e_w = (float*)(e_idx + nnz);
    int* n_idx = (int*)(e_w + nnz);
    float* n_w = (float*)(n_idx + nnz);
    float* Ye = n_w + nnz;
    float* Pn = Ye + (size_t)NEDGES * HID;

    // zero dv, de, e_off, n_off (contiguous)
    size_t zero_elems = (size_t)NNODES + NEDGES + (NEDGES + 1) + (NNODES + 1);
    hipMemsetAsync(dv, 0, zero_elems * 4, stream);

    deg_hist_kernel<<<(nnz + 255) / 256, 256, 0, stream>>>(
        rows, cols, vals, dv, de, e_off, n_off, nnz);
    inv_kernel<<<(NNODES + NEDGES + 255) / 256, 256, 0, stream>>>(dv, de);
    scan_excl_kernel<<<1, 1024, 0, stream>>>(e_off, e_cur, NEDGES + 1);
    scan_excl_kernel<<<1, 1024, 0, stream>>>(n_off, n_cur, NNODES + 1);
    build_kernel<<<(nnz + 255) / 256, 256, 0, stream>>>(
        rows, cols, vals, dv, de, e_cur, n_cur, e_idx, e_w, n_idx, n_w, nnz);

    const int eg_blocks = (NEDGES + 3) / 4;
    const int ng_blocks = (NNODES + 3) / 4;

    // ---- layer 1: X1 = relu((P @ X0) @ W0^T) -> d_out ----
    gather_kernel<<<eg_blocks, 256, 0, stream>>>(X0, Ye, e_off, e_idx, e_w, NEDGES);
    gather_kernel<<<ng_blocks, 256, 0, stream>>>(Ye, Pn, n_off, n_idx, n_w, NNODES);
    gemm_kernel<<<gemm_blocks, 256, 0, stream>>>(Pn, dv, W0, out, 1);

    // ---- layer 2: Z = (P @ X1) @ W1^T -> d_out ----
    gather_kernel<<<eg_blocks, 256, 0, stream>>>(out, Ye, e_off, e_idx, e_w, NEDGES);
    gather_kernel<<<ng_blocks, 256, 0, stream>>>(Ye, Pn, n_off, n_idx, n_w, NNODES);
    gemm_kernel<<<gemm_blocks, 256, 0, stream>>>(Pn, dv, W1, out, 0);
    return;
  }

  // ---------- fallback: R1 atomic-scatter path ----------
  float* dv = (float*)d_ws;
  float* de = dv + NNODES;
  float* Ye = de + NEDGES;
  float* Pn = Ye + (size_t)NEDGES * HID;
  const int scat_blocks = (nnz + 7) / 8;

  hipMemsetAsync(dv, 0, (size_t)(NNODES + NEDGES) * sizeof(float), stream);
  deg_hist_kernel<<<(nnz + 255) / 256, 256, 0, stream>>>(
      rows, cols, vals, dv, de, (int*)Ye /*unused scratch*/, (int*)Pn, nnz);
  // note: histogram outputs discarded in fallback; they land in Ye/Pn which
  // are re-zeroed below.
  inv_kernel<<<(NNODES + NEDGES + 255) / 256, 256, 0, stream>>>(dv, de);

  hipMemsetAsync(Ye, 0, (size_t)NEDGES * HID * sizeof(float), stream);
  scatter_edge_kernel<<<scat_blocks, 256, 0, stream>>>(X0, Ye, rows, cols, vals, dv, nnz);
  hipMemsetAsync(Pn, 0, (size_t)NNODES * HID * sizeof(float), stream);
  scatter_node_kernel<<<scat_blocks, 256, 0, stream>>>(Ye, Pn, rows, cols, vals, de, nnz);
  gemm_kernel<<<gemm_blocks, 256, 0, stream>>>(Pn, dv, W0, out, 1);

  hipMemsetAsync(Ye, 0, (size_t)NEDGES * HID * sizeof(float), stream);
  scatter_edge_kernel<<<scat_blocks, 256, 0, stream>>>(out, Ye, rows, cols, vals, dv, nnz);
  hipMemsetAsync(Pn, 0, (size_t)NNODES * HID * sizeof(float), stream);
  scatter_node_kernel<<<scat_blocks, 256, 0, stream>>>(Ye, Pn, rows, cols, vals, de, nnz);
  gemm_kernel<<<gemm_blocks, 256, 0, stream>>>(Pn, dv, W1, out, 0);
}

// Round 3
// 730.693 us; speedup vs baseline: 9.4408x; 1.3214x over previous
//
#include <hip/hip_runtime.h>
#include <math.h>

#define NNODES 50000
#define NEDGES 100000
#define HID 128
#define CNT_TOT (NNODES + NEDGES)  // 150000 combined segments
#define SCAN_BLK 1024              // elements per scan block (256 thr x 4)

// ===========================================================================
// histogram: cnt[c]++ (edge counts), cnt[NEDGES + r]++ (node counts)
// ===========================================================================
__global__ __launch_bounds__(256) void hist_kernel(
    const int* __restrict__ rows, const int* __restrict__ cols,
    int* __restrict__ cnt, int nnz) {
  int base = (blockIdx.x * 256 + threadIdx.x) * 4;
  if (base + 3 < nnz) {
    int4 r4 = *reinterpret_cast<const int4*>(rows + base);
    int4 c4 = *reinterpret_cast<const int4*>(cols + base);
    atomicAdd(&cnt[c4.x], 1);
    atomicAdd(&cnt[c4.y], 1);
    atomicAdd(&cnt[c4.z], 1);
    atomicAdd(&cnt[c4.w], 1);
    atomicAdd(&cnt[NEDGES + r4.x], 1);
    atomicAdd(&cnt[NEDGES + r4.y], 1);
    atomicAdd(&cnt[NEDGES + r4.z], 1);
    atomicAdd(&cnt[NEDGES + r4.w], 1);
  } else {
    for (int i = base; i < nnz; ++i) {
      atomicAdd(&cnt[cols[i]], 1);
      atomicAdd(&cnt[NEDGES + rows[i]], 1);
    }
  }
}

// ===========================================================================
// 3-kernel exclusive scan over cnt[0..n) (n = CNT_TOT+1), in-place -> off,
// plus a copy into cur.
// ===========================================================================
__global__ __launch_bounds__(256) void scan_part_kernel(
    const int* __restrict__ cnt, int* __restrict__ partials, int n) {
  int b = blockIdx.x, t = threadIdx.x;
  int i0 = b * SCAN_BLK + t * 4;
  int s = 0;
  if (i0 + 3 < n) {
    int4 v = *reinterpret_cast<const int4*>(cnt + i0);
    s = v.x + v.y + v.z + v.w;
  } else {
    for (int k = 0; k < 4; ++k)
      if (i0 + k < n) s += cnt[i0 + k];
  }
#pragma unroll
  for (int d = 1; d < 64; d <<= 1) s += __shfl_xor(s, d, 64);
  __shared__ int ws[4];
  if ((t & 63) == 0) ws[t >> 6] = s;
  __syncthreads();
  if (t == 0) partials[b] = ws[0] + ws[1] + ws[2] + ws[3];
}

__global__ __launch_bounds__(256) void scan_partials_kernel(
    int* __restrict__ partials, int nb) {
  int t = threadIdx.x;
  int lane = t & 63, wid = t >> 6;
  int x = (t < nb) ? partials[t] : 0;
  int incl = x;
#pragma unroll
  for (int d = 1; d < 64; d <<= 1) {
    int tt = __shfl_up(incl, d, 64);
    if (lane >= d) incl += tt;
  }
  __shared__ int ws[4];
  if (lane == 63) ws[wid] = incl;
  __syncthreads();
  int woff = 0;
  for (int k = 0; k < wid; ++k) woff += ws[k];
  if (t < nb) partials[t] = woff + incl - x;
}

// in-place: reads cnt (== off buffer), writes exclusive offsets back + cur copy
__global__ __launch_bounds__(256) void scan_apply_kernel(
    int* __restrict__ off, const int* __restrict__ partials,
    int* __restrict__ cur, int n) {
  int b = blockIdx.x, t = threadIdx.x;
  int lane = t & 63, wid = t >> 6;
  int i0 = b * SCAN_BLK + t * 4;
  int v0 = 0, v1 = 0, v2 = 0, v3 = 0;
  if (i0 + 3 < n) {
    int4 v = *reinterpret_cast<const int4*>(off + i0);
    v0 = v.x; v1 = v.y; v2 = v.z; v3 = v.w;
  } else {
    if (i0 < n) v0 = off[i0];
    if (i0 + 1 < n) v1 = off[i0 + 1];
    if (i0 + 2 < n) v2 = off[i0 + 2];
    if (i0 + 3 < n) v3 = off[i0 + 3];
  }
  int tsum = v0 + v1 + v2 + v3;
  int incl = tsum;
#pragma unroll
  for (int d = 1; d < 64; d <<= 1) {
    int tt = __shfl_up(incl, d, 64);
    if (lane >= d) incl += tt;
  }
  __shared__ int ws[4];
  if (lane == 63) ws[wid] = incl;
  __syncthreads();
  int base = partials[b];
  for (int k = 0; k < wid; ++k) base += ws[k];
  base += incl - tsum;
  if (i0 < n) {
    off[i0] = base;
    if (i0 < CNT_TOT) cur[i0] = base;
  }
  if (i0 + 1 < n) {
    int o = base + v0;
    off[i0 + 1] = o;
    if (i0 + 1 < CNT_TOT) cur[i0 + 1] = o;
  }
  if (i0 + 2 < n) {
    int o = base + v0 + v1;
    off[i0 + 2] = o;
    if (i0 + 2 < CNT_TOT) cur[i0 + 2] = o;
  }
  if (i0 + 3 < n) {
    int o = base + v0 + v1 + v2;
    off[i0 + 3] = o;
    if (i0 + 3 < CNT_TOT) cur[i0 + 3] = o;
  }
}

// ===========================================================================
// build combined adjacency: edge entries at [0,nnz), node entries [nnz,2nnz)
// pair[p] = (neighbor index, raw val)
// ===========================================================================
__global__ __launch_bounds__(256) void build_kernel(
    const int* __restrict__ rows, const int* __restrict__ cols,
    const float* __restrict__ vals, int* __restrict__ cur,
    int2* __restrict__ pair, int nnz) {
  int i = blockIdx.x * 256 + threadIdx.x;
  if (i >= nnz) return;
  int r = rows[i], c = cols[i];
  int v = __float_as_int(vals[i]);
  int p = atomicAdd(&cur[c], 1);
  pair[p] = make_int2(r, v);
  int q = atomicAdd(&cur[NEDGES + r], 1);
  pair[q] = make_int2(c, v);
}

// ===========================================================================
// per-segment degree sums -> inverse scales (no atomics)
// ===========================================================================
__global__ __launch_bounds__(256) void deg_kernel(
    const int* __restrict__ off, const int2* __restrict__ pair,
    float* __restrict__ dein, float* __restrict__ dvis) {
  int i = blockIdx.x * 256 + threadIdx.x;
  if (i >= CNT_TOT) return;
  int s = off[i], t = off[i + 1];
  float sum = 0.f;
  for (int j = s; j < t; ++j) sum += __int_as_float(pair[j].y);
  sum = fmaxf(sum, 1e-6f);
  if (i < NEDGES)
    dein[i] = 1.0f / sum;
  else
    dvis[i - NEDGES] = 1.0f / sqrtf(sum);
}

// Y = dvis (.) X   (row scale), float4 lanes
__global__ __launch_bounds__(256) void scalex_kernel(
    const float* __restrict__ X, const float* __restrict__ dvis,
    float* __restrict__ Y) {
  int i = blockIdx.x * 256 + threadIdx.x;
  if (i >= NNODES * 32) return;
  float s = dvis[i >> 5];
  float4 v = reinterpret_cast<const float4*>(X)[i];
  reinterpret_cast<float4*>(Y)[i] = make_float4(s * v.x, s * v.y, s * v.z, s * v.w);
}

// ===========================================================================
// one wave64 per segment: dst[e,:] = scale_e * sum_j w_j * src[idx_j,:]
// ===========================================================================
__global__ __launch_bounds__(256) void gather_kernel(
    const float* __restrict__ src, float* __restrict__ dst,
    const int* __restrict__ off, const int2* __restrict__ pair,
    const float* __restrict__ seg_scale, int nseg) {
  int e = blockIdx.x * 4 + (threadIdx.x >> 6);
  int lane = threadIdx.x & 63;
  if (e >= nseg) return;
  int s = off[e], t = off[e + 1];
  const float2* S2 = reinterpret_cast<const float2*>(src);
  float2 acc = make_float2(0.f, 0.f);
  int j = s;
  for (; j + 1 < t; j += 2) {
    int2 p0 = pair[j], p1 = pair[j + 1];
    float w0 = __int_as_float(p0.y), w1 = __int_as_float(p1.y);
    float2 x0 = S2[(size_t)p0.x * 64 + lane];
    float2 x1 = S2[(size_t)p1.x * 64 + lane];
    acc.x = fmaf(w0, x0.x, acc.x);
    acc.y = fmaf(w0, x0.y, acc.y);
    acc.x = fmaf(w1, x1.x, acc.x);
    acc.y = fmaf(w1, x1.y, acc.y);
  }
  if (j < t) {
    int2 p0 = pair[j];
    float w0 = __int_as_float(p0.y);
    float2 x0 = S2[(size_t)p0.x * 64 + lane];
    acc.x = fmaf(w0, x0.x, acc.x);
    acc.y = fmaf(w0, x0.y, acc.y);
  }
  if (seg_scale) {
    float sc = seg_scale[e];
    acc.x *= sc;
    acc.y *= sc;
  }
  reinterpret_cast<float2*>(dst)[(size_t)e * 64 + lane] = acc;
}

// ===========================================================================
// GEMM: acc = Pn[n,:] @ W^T; epilogue by mode:
//   0: out = s*acc              (final layer)
//   1: out = s*relu(s*acc)      (layer-1 output pre-scaled for next gather)
//   2: out = relu(s*acc)        (fallback layer-1, exact X1)
// ===========================================================================
__global__ __launch_bounds__(256) void gemm_kernel(
    const float* __restrict__ Pn, const float* __restrict__ dvis,
    const float* __restrict__ W, float* __restrict__ out, int mode) {
  __shared__ float WT[HID * HID];  // WT[k][j] = W[j][k]
  for (int idx = threadIdx.x; idx < HID * HID; idx += 256) {
    int j = idx >> 7;
    int k = idx & 127;
    WT[k * HID + j] = W[idx];
  }
  __syncthreads();

  int lane = threadIdx.x & 31;
  int grp = threadIdx.x >> 5;
  const float4* X4 = reinterpret_cast<const float4*>(Pn);
  const float4* WT4 = reinterpret_cast<const float4*>(WT);
  int base = blockIdx.x * 64;

  for (int it = 0; it < 4; ++it) {
    int r0 = base + it * 16 + grp * 2;
    int r1 = r0 + 1;
    int rr0 = r0 < NNODES ? r0 : NNODES - 1;
    int rr1 = r1 < NNODES ? r1 : NNODES - 1;
    float4 a0 = make_float4(0.f, 0.f, 0.f, 0.f);
    float4 a1 = make_float4(0.f, 0.f, 0.f, 0.f);
#pragma unroll 4
    for (int kk = 0; kk < 32; ++kk) {
      float4 x0 = X4[(size_t)rr0 * 32 + kk];
      float4 x1 = X4[(size_t)rr1 * 32 + kk];
      const float* x0p = reinterpret_cast<const float*>(&x0);
      const float* x1p = reinterpret_cast<const float*>(&x1);
#pragma unroll
      for (int q = 0; q < 4; ++q) {
        float4 w = WT4[(kk * 4 + q) * 32 + lane];
        a0.x += x0p[q] * w.x; a0.y += x0p[q] * w.y;
        a0.z += x0p[q] * w.z; a0.w += x0p[q] * w.w;
        a1.x += x1p[q] * w.x; a1.y += x1p[q] * w.y;
        a1.z += x1p[q] * w.z; a1.w += x1p[q] * w.w;
      }
    }
#pragma unroll
    for (int half = 0; half < 2; ++half) {
      int r = half ? r1 : r0;
      float4 a = half ? a1 : a0;
      if (r < NNODES) {
        float s = dvis[r];
        float4 o = make_float4(s * a.x, s * a.y, s * a.z, s * a.w);
        if (mode >= 1) {
          o.x = fmaxf(o.x, 0.f); o.y = fmaxf(o.y, 0.f);
          o.z = fmaxf(o.z, 0.f); o.w = fmaxf(o.w, 0.f);
          if (mode == 1) { o.x *= s; o.y *= s; o.z *= s; o.w *= s; }
        }
        reinterpret_cast<float4*>(out)[(size_t)r * 32 + lane] = o;
      }
    }
  }
}

// ===========================================================================
// Fallback (atomic-scatter) kernels — used only if workspace is too small
// ===========================================================================
__global__ __launch_bounds__(256) void deg_fb_kernel(
    const int* __restrict__ rows, const int* __restrict__ cols,
    const float* __restrict__ vals, float* __restrict__ dv,
    float* __restrict__ de, int nnz) {
  int i = blockIdx.x * 256 + threadIdx.x;
  if (i >= nnz) return;
  float v = vals[i];
  unsafeAtomicAdd(&dv[rows[i]], v);
  unsafeAtomicAdd(&de[cols[i]], v);
}

__global__ __launch_bounds__(256) void inv_kernel(float* __restrict__ dv,
                                                  float* __restrict__ de) {
  int i = blockIdx.x * 256 + threadIdx.x;
  if (i < NNODES) {
    dv[i] = 1.0f / sqrtf(fmaxf(dv[i], 1e-6f));
  } else if (i < NNODES + NEDGES) {
    int j = i - NNODES;
    de[j] = 1.0f / fmaxf(de[j], 1e-6f);
  }
}

__global__ __launch_bounds__(256) void scatter_edge_kernel(
    const float* __restrict__ X, float* __restrict__ Ye,
    const int* __restrict__ rows, const int* __restrict__ cols,
    const float* __restrict__ vals, const float* __restrict__ dvis, int nnz) {
  int g = (blockIdx.x * 256 + threadIdx.x) >> 5;
  int lane = threadIdx.x & 31;
  if (g >= nnz) return;
  int r = rows[g], c = cols[g];
  float s = vals[g] * dvis[r];
  float4 x = reinterpret_cast<const float4*>(X)[(size_t)r * 32 + lane];
  float* dst = Ye + (size_t)c * HID + lane * 4;
  unsafeAtomicAdd(dst + 0, s * x.x);
  unsafeAtomicAdd(dst + 1, s * x.y);
  unsafeAtomicAdd(dst + 2, s * x.z);
  unsafeAtomicAdd(dst + 3, s * x.w);
}

__global__ __launch_bounds__(256) void scatter_node_kernel(
    const float* __restrict__ Ye, float* __restrict__ Yn,
    const int* __restrict__ rows, const int* __restrict__ cols,
    const float* __restrict__ vals, const float* __restrict__ dein, int nnz) {
  int g = (blockIdx.x * 256 + threadIdx.x) >> 5;
  int lane = threadIdx.x & 31;
  if (g >= nnz) return;
  int r = rows[g], c = cols[g];
  float s = vals[g] * dein[c];
  float4 y = reinterpret_cast<const float4*>(Ye)[(size_t)c * 32 + lane];
  float* dst = Yn + (size_t)r * HID + lane * 4;
  unsafeAtomicAdd(dst + 0, s * y.x);
  unsafeAtomicAdd(dst + 1, s * y.y);
  unsafeAtomicAdd(dst + 2, s * y.z);
  unsafeAtomicAdd(dst + 3, s * y.w);
}

// ===========================================================================
extern "C" void kernel_launch(void* const* d_in, const int* in_sizes, int n_in,
                              void* d_out, int out_size, void* d_ws,
                              size_t ws_size, hipStream_t stream) {
  const int* rows = (const int*)d_in[0];
  const int* cols = (const int*)d_in[1];
  const float* vals = (const float*)d_in[2];
  const float* X0 = (const float*)d_in[3];
  const float* W0 = (const float*)d_in[4];
  const float* W1 = (const float*)d_in[5];
  const int nnz = in_sizes[0];
  float* out = (float*)d_out;

  const int gemm_blocks = (NNODES + 63) / 64;

  // workspace layout (CSR path):
  // pair[2*nnz int2] | Ye[E*HID] | Pn[N*HID] | dvis[N] | dein[E] |
  // off[CNT_TOT+1] | cur[CNT_TOT] | partials[256]
  size_t elems = 4 * (size_t)nnz + (size_t)NEDGES * HID + (size_t)NNODES * HID +
                 NNODES + NEDGES + (CNT_TOT + 1) + CNT_TOT + 256;
  size_t need = elems * 4;

  if (ws_size >= need) {
    int2* pair = (int2*)d_ws;
    float* Ye = (float*)(pair + 2 * (size_t)nnz);
    float* Pn = Ye + (size_t)NEDGES * HID;
    float* dvis = Pn + (size_t)NNODES * HID;
    float* dein = dvis + NNODES;
    int* off = (int*)(dein + NEDGES);
    int* cur = off + CNT_TOT + 1;
    int* partials = cur + CNT_TOT;

    const int nb = (CNT_TOT + 1 + SCAN_BLK - 1) / SCAN_BLK;  // 147

    hipMemsetAsync(off, 0, (size_t)(CNT_TOT + 1) * 4, stream);
    hist_kernel<<<(nnz / 4 + 255) / 256, 256, 0, stream>>>(rows, cols, off, nnz);
    scan_part_kernel<<<nb, 256, 0, stream>>>(off, partials, CNT_TOT + 1);
    scan_partials_kernel<<<1, 256, 0, stream>>>(partials, nb);
    scan_apply_kernel<<<nb, 256, 0, stream>>>(off, partials, cur, CNT_TOT + 1);
    build_kernel<<<(nnz + 255) / 256, 256, 0, stream>>>(rows, cols, vals, cur,
                                                        pair, nnz);
    deg_kernel<<<(CNT_TOT + 255) / 256, 256, 0, stream>>>(off, pair, dein, dvis);
    scalex_kernel<<<(NNODES * 32 + 255) / 256, 256, 0, stream>>>(X0, dvis, Pn);

    const int eg_blocks = (NEDGES + 3) / 4;
    const int ng_blocks = (NNODES + 3) / 4;

    // layer 1
    gather_kernel<<<eg_blocks, 256, 0, stream>>>(Pn, Ye, off, pair, dein, NEDGES);
    gather_kernel<<<ng_blocks, 256, 0, stream>>>(Ye, Pn, off + NEDGES, pair,
                                                 nullptr, NNODES);
    gemm_kernel<<<gemm_blocks, 256, 0, stream>>>(Pn, dvis, W0, out, 1);

    // layer 2
    gather_kernel<<<eg_blocks, 256, 0, stream>>>(out, Ye, off, pair, dein, NEDGES);
    gather_kernel<<<ng_blocks, 256, 0, stream>>>(Ye, Pn, off + NEDGES, pair,
                                                 nullptr, NNODES);
    gemm_kernel<<<gemm_blocks, 256, 0, stream>>>(Pn, dvis, W1, out, 0);
    return;
  }

  // ---------- fallback: atomic-scatter path ----------
  float* dv = (float*)d_ws;
  float* de = dv + NNODES;
  float* Ye = de + NEDGES;
  float* Pn = Ye + (size_t)NEDGES * HID;
  const int scat_blocks = (nnz + 7) / 8;

  hipMemsetAsync(dv, 0, (size_t)(NNODES + NEDGES) * sizeof(float), stream);
  deg_fb_kernel<<<(nnz + 255) / 256, 256, 0, stream>>>(rows, cols, vals, dv, de, nnz);
  inv_kernel<<<(NNODES + NEDGES + 255) / 256, 256, 0, stream>>>(dv, de);

  hipMemsetAsync(Ye, 0, (size_t)NEDGES * HID * sizeof(float), stream);
  scatter_edge_kernel<<<scat_blocks, 256, 0, stream>>>(X0, Ye, rows, cols, vals, dv, nnz);
  hipMemsetAsync(Pn, 0, (size_t)NNODES * HID * sizeof(float), stream);
  scatter_node_kernel<<<scat_blocks, 256, 0, stream>>>(Ye, Pn, rows, cols, vals, de, nnz);
  gemm_kernel<<<gemm_blocks, 256, 0, stream>>>(Pn, dv, W0, out, 2);

  hipMemsetAsync(Ye, 0, (size_t)NEDGES * HID * sizeof(float), stream);
  scatter_edge_kernel<<<scat_blocks, 256, 0, stream>>>(out, Ye, rows, cols, vals, dv, nnz);
  hipMemsetAsync(Pn, 0, (size_t)NNODES * HID * sizeof(float), stream);
  scatter_node_kernel<<<scat_blocks, 256, 0, stream>>>(Ye, Pn, rows, cols, vals, de, nnz);
  gemm_kernel<<<gemm_blocks, 256, 0, stream>>>(Pn, dv, W1, out, 0);
}

// Round 4
// 536.258 us; speedup vs baseline: 12.8638x; 1.3626x over previous
//
#include <hip/hip_runtime.h>
#include <math.h>

#define NNODES 50000
#define NEDGES 100000
#define HID 128
#define CNT_TOT (NNODES + NEDGES)  // 150000 combined segments

// bucket decomposition: 256 keys per bucket, edge buckets then node buckets
#define NB_E ((NEDGES + 255) >> 8)  // 391
#define NB_N ((NNODES + 255) >> 8)  // 196
#define NB (NB_E + NB_N)            // 587
#define PART_CHUNK 4096             // incidences per partition block

// ===========================================================================
// bucket_count: LDS histogram of bucket sizes (combined edge||node space)
// ===========================================================================
__global__ __launch_bounds__(256) void bucket_count_kernel(
    const int* __restrict__ rows, const int* __restrict__ cols,
    int* __restrict__ bucket_cnt, int nnz) {
  __shared__ int cnt[NB];
  for (int k = threadIdx.x; k < NB; k += 256) cnt[k] = 0;
  __syncthreads();
  int stride = gridDim.x * 256 * 4;
  for (int base = (blockIdx.x * 256 + threadIdx.x) * 4; base < nnz;
       base += stride) {
    if (base + 3 < nnz) {
      int4 r4 = *reinterpret_cast<const int4*>(rows + base);
      int4 c4 = *reinterpret_cast<const int4*>(cols + base);
      atomicAdd(&cnt[c4.x >> 8], 1);
      atomicAdd(&cnt[c4.y >> 8], 1);
      atomicAdd(&cnt[c4.z >> 8], 1);
      atomicAdd(&cnt[c4.w >> 8], 1);
      atomicAdd(&cnt[NB_E + (r4.x >> 8)], 1);
      atomicAdd(&cnt[NB_E + (r4.y >> 8)], 1);
      atomicAdd(&cnt[NB_E + (r4.z >> 8)], 1);
      atomicAdd(&cnt[NB_E + (r4.w >> 8)], 1);
    } else {
      for (int i = base; i < nnz; ++i) {
        atomicAdd(&cnt[cols[i] >> 8], 1);
        atomicAdd(&cnt[NB_E + (rows[i] >> 8)], 1);
      }
    }
  }
  __syncthreads();
  for (int k = threadIdx.x; k < NB; k += 256)
    if (cnt[k]) atomicAdd(&bucket_cnt[k], cnt[k]);
}

// exclusive scan of NB bucket counts (NB <= 1024), one block
__global__ __launch_bounds__(1024) void bucket_scan_kernel(
    const int* __restrict__ bucket_cnt, int* __restrict__ bucket_base,
    int* __restrict__ bucket_cur) {
  int t = threadIdx.x;
  int lane = t & 63, wid = t >> 6;
  int x = (t < NB) ? bucket_cnt[t] : 0;
  int incl = x;
#pragma unroll
  for (int d = 1; d < 64; d <<= 1) {
    int tt = __shfl_up(incl, d, 64);
    if (lane >= d) incl += tt;
  }
  __shared__ int ws[16];
  if (lane == 63) ws[wid] = incl;
  __syncthreads();
  int woff = 0;
  for (int k = 0; k < wid; ++k) woff += ws[k];
  int excl = woff + incl - x;
  if (t < NB) {
    bucket_base[t] = excl;
    bucket_cur[t] = excl;
  }
  if (t == NB - 1) bucket_base[NB] = excl + x;  // == 2*nnz
}

// ===========================================================================
// partition: per-block LDS hist -> chunk reserve -> write items to buckets
// item.x = (key_low8 << 18) | neighbor(17b), item.y = val bits
// ===========================================================================
__global__ __launch_bounds__(256) void partition_kernel(
    const int* __restrict__ rows, const int* __restrict__ cols,
    const float* __restrict__ vals, int* __restrict__ bucket_cur,
    int2* __restrict__ bkt_items, int nnz) {
  __shared__ int cnt[NB];
  __shared__ int wbase[NB];
  for (int k = threadIdx.x; k < NB; k += 256) cnt[k] = 0;
  __syncthreads();
  int start = blockIdx.x * PART_CHUNK;
  int end = start + PART_CHUNK;
  if (end > nnz) end = nnz;
  // phase 1: count
  for (int i = start + threadIdx.x; i < end; i += 256) {
    atomicAdd(&cnt[cols[i] >> 8], 1);
    atomicAdd(&cnt[NB_E + (rows[i] >> 8)], 1);
  }
  __syncthreads();
  // reserve global chunks, reset local cursors
  for (int k = threadIdx.x; k < NB; k += 256) {
    int c = cnt[k];
    wbase[k] = c ? atomicAdd(&bucket_cur[k], c) : 0;
    cnt[k] = 0;
  }
  __syncthreads();
  // phase 2: write
  for (int i = start + threadIdx.x; i < end; i += 256) {
    int c = cols[i], r = rows[i];
    int v = __float_as_int(vals[i]);
    int be = c >> 8;
    int p = wbase[be] + atomicAdd(&cnt[be], 1);
    bkt_items[p] = make_int2(((c & 255) << 18) | r, v);
    int bn = NB_E + (r >> 8);
    int q = wbase[bn] + atomicAdd(&cnt[bn], 1);
    bkt_items[q] = make_int2(((r & 255) << 18) | c, v);
  }
}

// ===========================================================================
// place: one block per bucket; per-key LDS hist+scan; writes off[] and pair[]
// ===========================================================================
__global__ __launch_bounds__(256) void place_kernel(
    const int* __restrict__ bucket_base, const int2* __restrict__ bkt_items,
    int* __restrict__ off, int2* __restrict__ pair) {
  int b = blockIdx.x;
  int s = bucket_base[b], e = bucket_base[b + 1];
  __shared__ int kcnt[256];
  __shared__ int kbase[256];
  __shared__ int ws[4];
  int t = threadIdx.x;
  kcnt[t] = 0;
  __syncthreads();
  for (int j = s + t; j < e; j += 256)
    atomicAdd(&kcnt[bkt_items[j].x >> 18], 1);
  __syncthreads();
  // exclusive scan of 256 per-key counts
  int x = kcnt[t];
  int lane = t & 63, wid = t >> 6;
  int incl = x;
#pragma unroll
  for (int d = 1; d < 64; d <<= 1) {
    int tt = __shfl_up(incl, d, 64);
    if (lane >= d) incl += tt;
  }
  if (lane == 63) ws[wid] = incl;
  __syncthreads();
  int woff = 0;
  for (int k = 0; k < wid; ++k) woff += ws[k];
  int excl = woff + incl - x;
  kbase[t] = s + excl;
  // write global segment offsets for this bucket's keys
  if (b < NB_E) {
    int kglob = (b << 8) | t;
    if (kglob < NEDGES) off[kglob] = s + excl;
  } else {
    int kglob = ((b - NB_E) << 8) | t;
    if (kglob < NNODES) off[NEDGES + kglob] = s + excl;
  }
  if (b == NB - 1 && t == 255) off[CNT_TOT] = e;
  __syncthreads();
  kcnt[t] = 0;
  __syncthreads();
  // place
  for (int j = s + t; j < e; j += 256) {
    int2 it = bkt_items[j];
    int k = it.x >> 18;
    int pos = kbase[k] + atomicAdd(&kcnt[k], 1);
    pair[pos] = make_int2(it.x & 0x3FFFF, it.y);
  }
}

// ===========================================================================
// per-segment degree sums -> inverse scales (no atomics)
// ===========================================================================
__global__ __launch_bounds__(256) void deg_kernel(
    const int* __restrict__ off, const int2* __restrict__ pair,
    float* __restrict__ dein, float* __restrict__ dvis) {
  int i = blockIdx.x * 256 + threadIdx.x;
  if (i >= CNT_TOT) return;
  int s = off[i], t = off[i + 1];
  float sum = 0.f;
  for (int j = s; j < t; ++j) sum += __int_as_float(pair[j].y);
  sum = fmaxf(sum, 1e-6f);
  if (i < NEDGES)
    dein[i] = 1.0f / sum;
  else
    dvis[i - NEDGES] = 1.0f / sqrtf(sum);
}

// Y = dvis (.) X   (row scale), float4 lanes
__global__ __launch_bounds__(256) void scalex_kernel(
    const float* __restrict__ X, const float* __restrict__ dvis,
    float* __restrict__ Y) {
  int i = blockIdx.x * 256 + threadIdx.x;
  if (i >= NNODES * 32) return;
  float s = dvis[i >> 5];
  float4 v = reinterpret_cast<const float4*>(X)[i];
  reinterpret_cast<float4*>(Y)[i] =
      make_float4(s * v.x, s * v.y, s * v.z, s * v.w);
}

// ===========================================================================
// one wave64 per segment: dst[e,:] = scale_e * sum_j w_j * src[idx_j,:]
// ===========================================================================
__global__ __launch_bounds__(256) void gather_kernel(
    const float* __restrict__ src, float* __restrict__ dst,
    const int* __restrict__ off, const int2* __restrict__ pair,
    const float* __restrict__ seg_scale, int nseg) {
  int e = blockIdx.x * 4 + (threadIdx.x >> 6);
  int lane = threadIdx.x & 63;
  if (e >= nseg) return;
  int s = off[e], t = off[e + 1];
  const float2* S2 = reinterpret_cast<const float2*>(src);
  float2 acc = make_float2(0.f, 0.f);
  int j = s;
  for (; j + 1 < t; j += 2) {
    int2 p0 = pair[j], p1 = pair[j + 1];
    float w0 = __int_as_float(p0.y), w1 = __int_as_float(p1.y);
    float2 x0 = S2[(size_t)p0.x * 64 + lane];
    float2 x1 = S2[(size_t)p1.x * 64 + lane];
    acc.x = fmaf(w0, x0.x, acc.x);
    acc.y = fmaf(w0, x0.y, acc.y);
    acc.x = fmaf(w1, x1.x, acc.x);
    acc.y = fmaf(w1, x1.y, acc.y);
  }
  if (j < t) {
    int2 p0 = pair[j];
    float w0 = __int_as_float(p0.y);
    float2 x0 = S2[(size_t)p0.x * 64 + lane];
    acc.x = fmaf(w0, x0.x, acc.x);
    acc.y = fmaf(w0, x0.y, acc.y);
  }
  if (seg_scale) {
    float sc = seg_scale[e];
    acc.x *= sc;
    acc.y *= sc;
  }
  reinterpret_cast<float2*>(dst)[(size_t)e * 64 + lane] = acc;
}

// ===========================================================================
// GEMM: acc = Pn[n,:] @ W^T; epilogue by mode:
//   0: out = s*acc              (final layer)
//   1: out = s*relu(s*acc)      (layer-1 output pre-scaled for next gather)
//   2: out = relu(s*acc)        (fallback layer-1, exact X1)
// ===========================================================================
__global__ __launch_bounds__(256) void gemm_kernel(
    const float* __restrict__ Pn, const float* __restrict__ dvis,
    const float* __restrict__ W, float* __restrict__ out, int mode) {
  __shared__ float WT[HID * HID];  // WT[k][j] = W[j][k]
  for (int idx = threadIdx.x; idx < HID * HID; idx += 256) {
    int j = idx >> 7;
    int k = idx & 127;
    WT[k * HID + j] = W[idx];
  }
  __syncthreads();

  int lane = threadIdx.x & 31;
  int grp = threadIdx.x >> 5;
  const float4* X4 = reinterpret_cast<const float4*>(Pn);
  const float4* WT4 = reinterpret_cast<const float4*>(WT);
  int base = blockIdx.x * 64;

  for (int it = 0; it < 4; ++it) {
    int r0 = base + it * 16 + grp * 2;
    int r1 = r0 + 1;
    int rr0 = r0 < NNODES ? r0 : NNODES - 1;
    int rr1 = r1 < NNODES ? r1 : NNODES - 1;
    float4 a0 = make_float4(0.f, 0.f, 0.f, 0.f);
    float4 a1 = make_float4(0.f, 0.f, 0.f, 0.f);
#pragma unroll 4
    for (int kk = 0; kk < 32; ++kk) {
      float4 x0 = X4[(size_t)rr0 * 32 + kk];
      float4 x1 = X4[(size_t)rr1 * 32 + kk];
      const float* x0p = reinterpret_cast<const float*>(&x0);
      const float* x1p = reinterpret_cast<const float*>(&x1);
#pragma unroll
      for (int q = 0; q < 4; ++q) {
        float4 w = WT4[(kk * 4 + q) * 32 + lane];
        a0.x += x0p[q] * w.x; a0.y += x0p[q] * w.y;
        a0.z += x0p[q] * w.z; a0.w += x0p[q] * w.w;
        a1.x += x1p[q] * w.x; a1.y += x1p[q] * w.y;
        a1.z += x1p[q] * w.z; a1.w += x1p[q] * w.w;
      }
    }
#pragma unroll
    for (int half = 0; half < 2; ++half) {
      int r = half ? r1 : r0;
      float4 a = half ? a1 : a0;
      if (r < NNODES) {
        float s = dvis[r];
        float4 o = make_float4(s * a.x, s * a.y, s * a.z, s * a.w);
        if (mode >= 1) {
          o.x = fmaxf(o.x, 0.f); o.y = fmaxf(o.y, 0.f);
          o.z = fmaxf(o.z, 0.f); o.w = fmaxf(o.w, 0.f);
          if (mode == 1) { o.x *= s; o.y *= s; o.z *= s; o.w *= s; }
        }
        reinterpret_cast<float4*>(out)[(size_t)r * 32 + lane] = o;
      }
    }
  }
}

// ===========================================================================
// Fallback (atomic-scatter) kernels — used only if workspace is too small
// ===========================================================================
__global__ __launch_bounds__(256) void deg_fb_kernel(
    const int* __restrict__ rows, const int* __restrict__ cols,
    const float* __restrict__ vals, float* __restrict__ dv,
    float* __restrict__ de, int nnz) {
  int i = blockIdx.x * 256 + threadIdx.x;
  if (i >= nnz) return;
  float v = vals[i];
  unsafeAtomicAdd(&dv[rows[i]], v);
  unsafeAtomicAdd(&de[cols[i]], v);
}

__global__ __launch_bounds__(256) void inv_kernel(float* __restrict__ dv,
                                                  float* __restrict__ de) {
  int i = blockIdx.x * 256 + threadIdx.x;
  if (i < NNODES) {
    dv[i] = 1.0f / sqrtf(fmaxf(dv[i], 1e-6f));
  } else if (i < NNODES + NEDGES) {
    int j = i - NNODES;
    de[j] = 1.0f / fmaxf(de[j], 1e-6f);
  }
}

__global__ __launch_bounds__(256) void scatter_edge_kernel(
    const float* __restrict__ X, float* __restrict__ Ye,
    const int* __restrict__ rows, const int* __restrict__ cols,
    const float* __restrict__ vals, const float* __restrict__ dvis, int nnz) {
  int g = (blockIdx.x * 256 + threadIdx.x) >> 5;
  int lane = threadIdx.x & 31;
  if (g >= nnz) return;
  int r = rows[g], c = cols[g];
  float s = vals[g] * dvis[r];
  float4 x = reinterpret_cast<const float4*>(X)[(size_t)r * 32 + lane];
  float* dst = Ye + (size_t)c * HID + lane * 4;
  unsafeAtomicAdd(dst + 0, s * x.x);
  unsafeAtomicAdd(dst + 1, s * x.y);
  unsafeAtomicAdd(dst + 2, s * x.z);
  unsafeAtomicAdd(dst + 3, s * x.w);
}

__global__ __launch_bounds__(256) void scatter_node_kernel(
    const float* __restrict__ Ye, float* __restrict__ Yn,
    const int* __restrict__ rows, const int* __restrict__ cols,
    const float* __restrict__ vals, const float* __restrict__ dein, int nnz) {
  int g = (blockIdx.x * 256 + threadIdx.x) >> 5;
  int lane = threadIdx.x & 31;
  if (g >= nnz) return;
  int r = rows[g], c = cols[g];
  float s = vals[g] * dein[c];
  float4 y = reinterpret_cast<const float4*>(Ye)[(size_t)c * 32 + lane];
  float* dst = Yn + (size_t)r * HID + lane * 4;
  unsafeAtomicAdd(dst + 0, s * y.x);
  unsafeAtomicAdd(dst + 1, s * y.y);
  unsafeAtomicAdd(dst + 2, s * y.z);
  unsafeAtomicAdd(dst + 3, s * y.w);
}

// ===========================================================================
extern "C" void kernel_launch(void* const* d_in, const int* in_sizes, int n_in,
                              void* d_out, int out_size, void* d_ws,
                              size_t ws_size, hipStream_t stream) {
  const int* rows = (const int*)d_in[0];
  const int* cols = (const int*)d_in[1];
  const float* vals = (const float*)d_in[2];
  const float* X0 = (const float*)d_in[3];
  const float* W0 = (const float*)d_in[4];
  const float* W1 = (const float*)d_in[5];
  const int nnz = in_sizes[0];
  float* out = (float*)d_out;

  const int gemm_blocks = (NNODES + 63) / 64;

  // workspace layout (CSR path):
  // pair[2*nnz int2] | Ye[E*HID] (bkt_items[2*nnz int2] lives here during
  // preprocessing) | Pn[N*HID] | dvis[N] | dein[E] | off[CNT_TOT+1] |
  // bucket_cnt[NB] | bucket_base[NB+1] | bucket_cur[NB]
  size_t elems = 4 * (size_t)nnz + (size_t)NEDGES * HID +
                 (size_t)NNODES * HID + NNODES + NEDGES + (CNT_TOT + 1) +
                 NB + (NB + 1) + NB;
  size_t need = elems * 4;
  bool bkt_fits = (size_t)4 * nnz <= (size_t)NEDGES * HID;  // bkt_items in Ye

  if (ws_size >= need && bkt_fits) {
    int2* pair = (int2*)d_ws;
    float* Ye = (float*)(pair + 2 * (size_t)nnz);
    int2* bkt_items = (int2*)Ye;  // preprocessing-only alias
    float* Pn = Ye + (size_t)NEDGES * HID;
    float* dvis = Pn + (size_t)NNODES * HID;
    float* dein = dvis + NNODES;
    int* off = (int*)(dein + NEDGES);
    int* bucket_cnt = off + CNT_TOT + 1;
    int* bucket_base = bucket_cnt + NB;
    int* bucket_cur = bucket_base + NB + 1;

    hipMemsetAsync(bucket_cnt, 0, NB * sizeof(int), stream);
    bucket_count_kernel<<<240, 256, 0, stream>>>(rows, cols, bucket_cnt, nnz);
    bucket_scan_kernel<<<1, 1024, 0, stream>>>(bucket_cnt, bucket_base,
                                               bucket_cur);
    partition_kernel<<<(nnz + PART_CHUNK - 1) / PART_CHUNK, 256, 0, stream>>>(
        rows, cols, vals, bucket_cur, bkt_items, nnz);
    place_kernel<<<NB, 256, 0, stream>>>(bucket_base, bkt_items, off, pair);
    deg_kernel<<<(CNT_TOT + 255) / 256, 256, 0, stream>>>(off, pair, dein,
                                                          dvis);
    scalex_kernel<<<(NNODES * 32 + 255) / 256, 256, 0, stream>>>(X0, dvis, Pn);

    const int eg_blocks = (NEDGES + 3) / 4;
    const int ng_blocks = (NNODES + 3) / 4;

    // layer 1
    gather_kernel<<<eg_blocks, 256, 0, stream>>>(Pn, Ye, off, pair, dein,
                                                 NEDGES);
    gather_kernel<<<ng_blocks, 256, 0, stream>>>(Ye, Pn, off + NEDGES, pair,
                                                 nullptr, NNODES);
    gemm_kernel<<<gemm_blocks, 256, 0, stream>>>(Pn, dvis, W0, out, 1);

    // layer 2
    gather_kernel<<<eg_blocks, 256, 0, stream>>>(out, Ye, off, pair, dein,
                                                 NEDGES);
    gather_kernel<<<ng_blocks, 256, 0, stream>>>(Ye, Pn, off + NEDGES, pair,
                                                 nullptr, NNODES);
    gemm_kernel<<<gemm_blocks, 256, 0, stream>>>(Pn, dvis, W1, out, 0);
    return;
  }

  // ---------- fallback: atomic-scatter path ----------
  float* dv = (float*)d_ws;
  float* de = dv + NNODES;
  float* Ye = de + NEDGES;
  float* Pn = Ye + (size_t)NEDGES * HID;
  const int scat_blocks = (nnz + 7) / 8;

  hipMemsetAsync(dv, 0, (size_t)(NNODES + NEDGES) * sizeof(float), stream);
  deg_fb_kernel<<<(nnz + 255) / 256, 256, 0, stream>>>(rows, cols, vals, dv,
                                                       de, nnz);
  inv_kernel<<<(NNODES + NEDGES + 255) / 256, 256, 0, stream>>>(dv, de);

  hipMemsetAsync(Ye, 0, (size_t)NEDGES * HID * sizeof(float), stream);
  scatter_edge_kernel<<<scat_blocks, 256, 0, stream>>>(X0, Ye, rows, cols,
                                                       vals, dv, nnz);
  hipMemsetAsync(Pn, 0, (size_t)NNODES * HID * sizeof(float), stream);
  scatter_node_kernel<<<scat_blocks, 256, 0, stream>>>(Ye, Pn, rows, cols,
                                                       vals, de, nnz);
  gemm_kernel<<<gemm_blocks, 256, 0, stream>>>(Pn, dv, W0, out, 2);

  hipMemsetAsync(Ye, 0, (size_t)NEDGES * HID * sizeof(float), stream);
  scatter_edge_kernel<<<scat_blocks, 256, 0, stream>>>(out, Ye, rows, cols,
                                                       vals, dv, nnz);
  hipMemsetAsync(Pn, 0, (size_t)NNODES * HID * sizeof(float), stream);
  scatter_node_kernel<<<scat_blocks, 256, 0, stream>>>(Ye, Pn, rows, cols,
                                                       vals, de, nnz);
  gemm_kernel<<<gemm_blocks, 256, 0, stream>>>(Pn, dv, W1, out, 0);
}

// Round 5
// 502.320 us; speedup vs baseline: 13.7329x; 1.0676x over previous
//
#include <hip/hip_runtime.h>
#include <math.h>

#define NNODES 50000
#define NEDGES 100000
#define HID 128
#define CNT_TOT (NNODES + NEDGES)  // 150000 combined segments

// bucket decomposition: 256 keys per bucket, edge buckets then node buckets
#define NB_E ((NEDGES + 255) >> 8)  // 391
#define NB_N ((NNODES + 255) >> 8)  // 196
#define NB (NB_E + NB_N)            // 587
#define PART_CHUNK 4096             // incidences per partition block

// ===========================================================================
// bucket_count: LDS histogram of bucket sizes (combined edge||node space)
// ===========================================================================
__global__ __launch_bounds__(256) void bucket_count_kernel(
    const int* __restrict__ rows, const int* __restrict__ cols,
    int* __restrict__ bucket_cnt, int nnz) {
  __shared__ int cnt[NB];
  for (int k = threadIdx.x; k < NB; k += 256) cnt[k] = 0;
  __syncthreads();
  int stride = gridDim.x * 256 * 4;
  for (int base = (blockIdx.x * 256 + threadIdx.x) * 4; base < nnz;
       base += stride) {
    if (base + 3 < nnz) {
      int4 r4 = *reinterpret_cast<const int4*>(rows + base);
      int4 c4 = *reinterpret_cast<const int4*>(cols + base);
      atomicAdd(&cnt[c4.x >> 8], 1);
      atomicAdd(&cnt[c4.y >> 8], 1);
      atomicAdd(&cnt[c4.z >> 8], 1);
      atomicAdd(&cnt[c4.w >> 8], 1);
      atomicAdd(&cnt[NB_E + (r4.x >> 8)], 1);
      atomicAdd(&cnt[NB_E + (r4.y >> 8)], 1);
      atomicAdd(&cnt[NB_E + (r4.z >> 8)], 1);
      atomicAdd(&cnt[NB_E + (r4.w >> 8)], 1);
    } else {
      for (int i = base; i < nnz; ++i) {
        atomicAdd(&cnt[cols[i] >> 8], 1);
        atomicAdd(&cnt[NB_E + (rows[i] >> 8)], 1);
      }
    }
  }
  __syncthreads();
  for (int k = threadIdx.x; k < NB; k += 256)
    if (cnt[k]) atomicAdd(&bucket_cnt[k], cnt[k]);
}

// exclusive scan of NB bucket counts (NB <= 1024), one block
__global__ __launch_bounds__(1024) void bucket_scan_kernel(
    const int* __restrict__ bucket_cnt, int* __restrict__ bucket_base,
    int* __restrict__ bucket_cur) {
  int t = threadIdx.x;
  int lane = t & 63, wid = t >> 6;
  int x = (t < NB) ? bucket_cnt[t] : 0;
  int incl = x;
#pragma unroll
  for (int d = 1; d < 64; d <<= 1) {
    int tt = __shfl_up(incl, d, 64);
    if (lane >= d) incl += tt;
  }
  __shared__ int ws[16];
  if (lane == 63) ws[wid] = incl;
  __syncthreads();
  int woff = 0;
  for (int k = 0; k < wid; ++k) woff += ws[k];
  int excl = woff + incl - x;
  if (t < NB) {
    bucket_base[t] = excl;
    bucket_cur[t] = excl;
  }
  if (t == NB - 1) bucket_base[NB] = excl + x;  // == 2*nnz
}

// ===========================================================================
// partition: per-block LDS hist -> chunk reserve -> write items to buckets
// item.x = (key_low8 << 18) | neighbor(17b), item.y = val bits
// ===========================================================================
__global__ __launch_bounds__(256) void partition_kernel(
    const int* __restrict__ rows, const int* __restrict__ cols,
    const float* __restrict__ vals, int* __restrict__ bucket_cur,
    int2* __restrict__ bkt_items, int nnz) {
  __shared__ int cnt[NB];
  __shared__ int wbase[NB];
  for (int k = threadIdx.x; k < NB; k += 256) cnt[k] = 0;
  __syncthreads();
  int start = blockIdx.x * PART_CHUNK;
  int end = start + PART_CHUNK;
  if (end > nnz) end = nnz;
  // phase 1: count
  for (int i = start + threadIdx.x; i < end; i += 256) {
    atomicAdd(&cnt[cols[i] >> 8], 1);
    atomicAdd(&cnt[NB_E + (rows[i] >> 8)], 1);
  }
  __syncthreads();
  // reserve global chunks, reset local cursors
  for (int k = threadIdx.x; k < NB; k += 256) {
    int c = cnt[k];
    wbase[k] = c ? atomicAdd(&bucket_cur[k], c) : 0;
    cnt[k] = 0;
  }
  __syncthreads();
  // phase 2: write
  for (int i = start + threadIdx.x; i < end; i += 256) {
    int c = cols[i], r = rows[i];
    int v = __float_as_int(vals[i]);
    int be = c >> 8;
    int p = wbase[be] + atomicAdd(&cnt[be], 1);
    bkt_items[p] = make_int2(((c & 255) << 18) | r, v);
    int bn = NB_E + (r >> 8);
    int q = wbase[bn] + atomicAdd(&cnt[bn], 1);
    bkt_items[q] = make_int2(((r & 255) << 18) | c, v);
  }
}

// ===========================================================================
// place: one block per bucket; per-key LDS hist+scan; writes off[] and pair[]
// ===========================================================================
__global__ __launch_bounds__(256) void place_kernel(
    const int* __restrict__ bucket_base, const int2* __restrict__ bkt_items,
    int* __restrict__ off, int2* __restrict__ pair) {
  int b = blockIdx.x;
  int s = bucket_base[b], e = bucket_base[b + 1];
  __shared__ int kcnt[256];
  __shared__ int kbase[256];
  __shared__ int ws[4];
  int t = threadIdx.x;
  kcnt[t] = 0;
  __syncthreads();
  for (int j = s + t; j < e; j += 256)
    atomicAdd(&kcnt[bkt_items[j].x >> 18], 1);
  __syncthreads();
  // exclusive scan of 256 per-key counts
  int x = kcnt[t];
  int lane = t & 63, wid = t >> 6;
  int incl = x;
#pragma unroll
  for (int d = 1; d < 64; d <<= 1) {
    int tt = __shfl_up(incl, d, 64);
    if (lane >= d) incl += tt;
  }
  if (lane == 63) ws[wid] = incl;
  __syncthreads();
  int woff = 0;
  for (int k = 0; k < wid; ++k) woff += ws[k];
  int excl = woff + incl - x;
  kbase[t] = s + excl;
  // write global segment offsets for this bucket's keys
  if (b < NB_E) {
    int kglob = (b << 8) | t;
    if (kglob < NEDGES) off[kglob] = s + excl;
  } else {
    int kglob = ((b - NB_E) << 8) | t;
    if (kglob < NNODES) off[NEDGES + kglob] = s + excl;
  }
  if (b == NB - 1 && t == 255) off[CNT_TOT] = e;
  __syncthreads();
  kcnt[t] = 0;
  __syncthreads();
  // place
  for (int j = s + t; j < e; j += 256) {
    int2 it = bkt_items[j];
    int k = it.x >> 18;
    int pos = kbase[k] + atomicAdd(&kcnt[k], 1);
    pair[pos] = make_int2(it.x & 0x3FFFF, it.y);
  }
}

// ===========================================================================
// per-segment degree sums -> inverse scales (no atomics)
// ===========================================================================
__global__ __launch_bounds__(256) void deg_kernel(
    const int* __restrict__ off, const int2* __restrict__ pair,
    float* __restrict__ dein, float* __restrict__ dvis) {
  int i = blockIdx.x * 256 + threadIdx.x;
  if (i >= CNT_TOT) return;
  int s = off[i], t = off[i + 1];
  float sum = 0.f;
  for (int j = s; j < t; ++j) sum += __int_as_float(pair[j].y);
  sum = fmaxf(sum, 1e-6f);
  if (i < NEDGES)
    dein[i] = 1.0f / sum;
  else
    dvis[i - NEDGES] = 1.0f / sqrtf(sum);
}

// Y = dvis (.) X   (row scale), float4 lanes
__global__ __launch_bounds__(256) void scalex_kernel(
    const float* __restrict__ X, const float* __restrict__ dvis,
    float* __restrict__ Y) {
  int i = blockIdx.x * 256 + threadIdx.x;
  if (i >= NNODES * 32) return;
  float s = dvis[i >> 5];
  float4 v = reinterpret_cast<const float4*>(X)[i];
  reinterpret_cast<float4*>(Y)[i] =
      make_float4(s * v.x, s * v.y, s * v.z, s * v.w);
}

// ===========================================================================
// gather v2: one wave64 per segment, split into two 32-lane halves.
// Half h accumulates incidences j = s+h, s+h+2, ... reading full rows as
// float4 (1 KB per wave-instruction, covering 2 incidences). 2-deep unroll
// keeps ~2 KB in flight per wave. Halves combined via shfl_xor(32).
// ===========================================================================
__global__ __launch_bounds__(256) void gather_kernel(
    const float* __restrict__ src, float* __restrict__ dst,
    const int* __restrict__ off, const int2* __restrict__ pair,
    const float* __restrict__ seg_scale, int nseg) {
  int e = blockIdx.x * 4 + (threadIdx.x >> 6);
  if (e >= nseg) return;
  int lane = threadIdx.x & 63;
  int h = lane >> 5, lc = lane & 31;
  int s = off[e], t = off[e + 1];
  const float4* S4 = reinterpret_cast<const float4*>(src);
  float4 acc = make_float4(0.f, 0.f, 0.f, 0.f);
  int j = s + h;
  for (; j + 2 < t; j += 4) {
    int2 p0 = pair[j];
    int2 p1 = pair[j + 2];
    float w0 = __int_as_float(p0.y);
    float w1 = __int_as_float(p1.y);
    float4 x0 = S4[(size_t)p0.x * 32 + lc];
    float4 x1 = S4[(size_t)p1.x * 32 + lc];
    acc.x = fmaf(w0, x0.x, acc.x);
    acc.y = fmaf(w0, x0.y, acc.y);
    acc.z = fmaf(w0, x0.z, acc.z);
    acc.w = fmaf(w0, x0.w, acc.w);
    acc.x = fmaf(w1, x1.x, acc.x);
    acc.y = fmaf(w1, x1.y, acc.y);
    acc.z = fmaf(w1, x1.z, acc.z);
    acc.w = fmaf(w1, x1.w, acc.w);
  }
  if (j < t) {
    int2 p0 = pair[j];
    float w0 = __int_as_float(p0.y);
    float4 x0 = S4[(size_t)p0.x * 32 + lc];
    acc.x = fmaf(w0, x0.x, acc.x);
    acc.y = fmaf(w0, x0.y, acc.y);
    acc.z = fmaf(w0, x0.z, acc.z);
    acc.w = fmaf(w0, x0.w, acc.w);
  }
  // combine even/odd halves (same columns in both halves)
  acc.x += __shfl_xor(acc.x, 32);
  acc.y += __shfl_xor(acc.y, 32);
  acc.z += __shfl_xor(acc.z, 32);
  acc.w += __shfl_xor(acc.w, 32);
  if (seg_scale) {
    float sc = seg_scale[e];
    acc.x *= sc;
    acc.y *= sc;
    acc.z *= sc;
    acc.w *= sc;
  }
  if (h == 0)
    reinterpret_cast<float4*>(dst)[(size_t)e * 32 + lc] = acc;
}

// ===========================================================================
// GEMM: acc = Pn[n,:] @ W^T; epilogue by mode:
//   0: out = s*acc              (final layer)
//   1: out = s*relu(s*acc)      (layer-1 output pre-scaled for next gather)
//   2: out = relu(s*acc)        (fallback layer-1, exact X1)
// ===========================================================================
__global__ __launch_bounds__(256) void gemm_kernel(
    const float* __restrict__ Pn, const float* __restrict__ dvis,
    const float* __restrict__ W, float* __restrict__ out, int mode) {
  __shared__ float WT[HID * HID];  // WT[k][j] = W[j][k]
  for (int idx = threadIdx.x; idx < HID * HID; idx += 256) {
    int j = idx >> 7;
    int k = idx & 127;
    WT[k * HID + j] = W[idx];
  }
  __syncthreads();

  int lane = threadIdx.x & 31;
  int grp = threadIdx.x >> 5;
  const float4* X4 = reinterpret_cast<const float4*>(Pn);
  const float4* WT4 = reinterpret_cast<const float4*>(WT);
  int base = blockIdx.x * 64;

  for (int it = 0; it < 4; ++it) {
    int r0 = base + it * 16 + grp * 2;
    int r1 = r0 + 1;
    int rr0 = r0 < NNODES ? r0 : NNODES - 1;
    int rr1 = r1 < NNODES ? r1 : NNODES - 1;
    float4 a0 = make_float4(0.f, 0.f, 0.f, 0.f);
    float4 a1 = make_float4(0.f, 0.f, 0.f, 0.f);
#pragma unroll 4
    for (int kk = 0; kk < 32; ++kk) {
      float4 x0 = X4[(size_t)rr0 * 32 + kk];
      float4 x1 = X4[(size_t)rr1 * 32 + kk];
      const float* x0p = reinterpret_cast<const float*>(&x0);
      const float* x1p = reinterpret_cast<const float*>(&x1);
#pragma unroll
      for (int q = 0; q < 4; ++q) {
        float4 w = WT4[(kk * 4 + q) * 32 + lane];
        a0.x += x0p[q] * w.x; a0.y += x0p[q] * w.y;
        a0.z += x0p[q] * w.z; a0.w += x0p[q] * w.w;
        a1.x += x1p[q] * w.x; a1.y += x1p[q] * w.y;
        a1.z += x1p[q] * w.z; a1.w += x1p[q] * w.w;
      }
    }
#pragma unroll
    for (int half = 0; half < 2; ++half) {
      int r = half ? r1 : r0;
      float4 a = half ? a1 : a0;
      if (r < NNODES) {
        float s = dvis[r];
        float4 o = make_float4(s * a.x, s * a.y, s * a.z, s * a.w);
        if (mode >= 1) {
          o.x = fmaxf(o.x, 0.f); o.y = fmaxf(o.y, 0.f);
          o.z = fmaxf(o.z, 0.f); o.w = fmaxf(o.w, 0.f);
          if (mode == 1) { o.x *= s; o.y *= s; o.z *= s; o.w *= s; }
        }
        reinterpret_cast<float4*>(out)[(size_t)r * 32 + lane] = o;
      }
    }
  }
}

// ===========================================================================
// Fallback (atomic-scatter) kernels — used only if workspace is too small
// ===========================================================================
__global__ __launch_bounds__(256) void deg_fb_kernel(
    const int* __restrict__ rows, const int* __restrict__ cols,
    const float* __restrict__ vals, float* __restrict__ dv,
    float* __restrict__ de, int nnz) {
  int i = blockIdx.x * 256 + threadIdx.x;
  if (i >= nnz) return;
  float v = vals[i];
  unsafeAtomicAdd(&dv[rows[i]], v);
  unsafeAtomicAdd(&de[cols[i]], v);
}

__global__ __launch_bounds__(256) void inv_kernel(float* __restrict__ dv,
                                                  float* __restrict__ de) {
  int i = blockIdx.x * 256 + threadIdx.x;
  if (i < NNODES) {
    dv[i] = 1.0f / sqrtf(fmaxf(dv[i], 1e-6f));
  } else if (i < NNODES + NEDGES) {
    int j = i - NNODES;
    de[j] = 1.0f / fmaxf(de[j], 1e-6f);
  }
}

__global__ __launch_bounds__(256) void scatter_edge_kernel(
    const float* __restrict__ X, float* __restrict__ Ye,
    const int* __restrict__ rows, const int* __restrict__ cols,
    const float* __restrict__ vals, const float* __restrict__ dvis, int nnz) {
  int g = (blockIdx.x * 256 + threadIdx.x) >> 5;
  int lane = threadIdx.x & 31;
  if (g >= nnz) return;
  int r = rows[g], c = cols[g];
  float s = vals[g] * dvis[r];
  float4 x = reinterpret_cast<const float4*>(X)[(size_t)r * 32 + lane];
  float* dst = Ye + (size_t)c * HID + lane * 4;
  unsafeAtomicAdd(dst + 0, s * x.x);
  unsafeAtomicAdd(dst + 1, s * x.y);
  unsafeAtomicAdd(dst + 2, s * x.z);
  unsafeAtomicAdd(dst + 3, s * x.w);
}

__global__ __launch_bounds__(256) void scatter_node_kernel(
    const float* __restrict__ Ye, float* __restrict__ Yn,
    const int* __restrict__ rows, const int* __restrict__ cols,
    const float* __restrict__ vals, const float* __restrict__ dein, int nnz) {
  int g = (blockIdx.x * 256 + threadIdx.x) >> 5;
  int lane = threadIdx.x & 31;
  if (g >= nnz) return;
  int r = rows[g], c = cols[g];
  float s = vals[g] * dein[c];
  float4 y = reinterpret_cast<const float4*>(Ye)[(size_t)c * 32 + lane];
  float* dst = Yn + (size_t)r * HID + lane * 4;
  unsafeAtomicAdd(dst + 0, s * y.x);
  unsafeAtomicAdd(dst + 1, s * y.y);
  unsafeAtomicAdd(dst + 2, s * y.z);
  unsafeAtomicAdd(dst + 3, s * y.w);
}

// ===========================================================================
extern "C" void kernel_launch(void* const* d_in, const int* in_sizes, int n_in,
                              void* d_out, int out_size, void* d_ws,
                              size_t ws_size, hipStream_t stream) {
  const int* rows = (const int*)d_in[0];
  const int* cols = (const int*)d_in[1];
  const float* vals = (const float*)d_in[2];
  const float* X0 = (const float*)d_in[3];
  const float* W0 = (const float*)d_in[4];
  const float* W1 = (const float*)d_in[5];
  const int nnz = in_sizes[0];
  float* out = (float*)d_out;

  const int gemm_blocks = (NNODES + 63) / 64;

  // workspace layout (CSR path):
  // pair[2*nnz int2] | Ye[E*HID] (bkt_items[2*nnz int2] lives here during
  // preprocessing) | Pn[N*HID] | dvis[N] | dein[E] | off[CNT_TOT+1] |
  // bucket_cnt[NB] | bucket_base[NB+1] | bucket_cur[NB]
  size_t elems = 4 * (size_t)nnz + (size_t)NEDGES * HID +
                 (size_t)NNODES * HID + NNODES + NEDGES + (CNT_TOT + 1) +
                 NB + (NB + 1) + NB;
  size_t need = elems * 4;
  bool bkt_fits = (size_t)4 * nnz <= (size_t)NEDGES * HID;  // bkt_items in Ye

  if (ws_size >= need && bkt_fits) {
    int2* pair = (int2*)d_ws;
    float* Ye = (float*)(pair + 2 * (size_t)nnz);
    int2* bkt_items = (int2*)Ye;  // preprocessing-only alias
    float* Pn = Ye + (size_t)NEDGES * HID;
    float* dvis = Pn + (size_t)NNODES * HID;
    float* dein = dvis + NNODES;
    int* off = (int*)(dein + NEDGES);
    int* bucket_cnt = off + CNT_TOT + 1;
    int* bucket_base = bucket_cnt + NB;
    int* bucket_cur = bucket_base + NB + 1;

    hipMemsetAsync(bucket_cnt, 0, NB * sizeof(int), stream);
    bucket_count_kernel<<<240, 256, 0, stream>>>(rows, cols, bucket_cnt, nnz);
    bucket_scan_kernel<<<1, 1024, 0, stream>>>(bucket_cnt, bucket_base,
                                               bucket_cur);
    partition_kernel<<<(nnz + PART_CHUNK - 1) / PART_CHUNK, 256, 0, stream>>>(
        rows, cols, vals, bucket_cur, bkt_items, nnz);
    place_kernel<<<NB, 256, 0, stream>>>(bucket_base, bkt_items, off, pair);
    deg_kernel<<<(CNT_TOT + 255) / 256, 256, 0, stream>>>(off, pair, dein,
                                                          dvis);
    scalex_kernel<<<(NNODES * 32 + 255) / 256, 256, 0, stream>>>(X0, dvis, Pn);

    const int eg_blocks = (NEDGES + 3) / 4;
    const int ng_blocks = (NNODES + 3) / 4;

    // layer 1
    gather_kernel<<<eg_blocks, 256, 0, stream>>>(Pn, Ye, off, pair, dein,
                                                 NEDGES);
    gather_kernel<<<ng_blocks, 256, 0, stream>>>(Ye, Pn, off + NEDGES, pair,
                                                 nullptr, NNODES);
    gemm_kernel<<<gemm_blocks, 256, 0, stream>>>(Pn, dvis, W0, out, 1);

    // layer 2
    gather_kernel<<<eg_blocks, 256, 0, stream>>>(out, Ye, off, pair, dein,
                                                 NEDGES);
    gather_kernel<<<ng_blocks, 256, 0, stream>>>(Ye, Pn, off + NEDGES, pair,
                                                 nullptr, NNODES);
    gemm_kernel<<<gemm_blocks, 256, 0, stream>>>(Pn, dvis, W1, out, 0);
    return;
  }

  // ---------- fallback: atomic-scatter path ----------
  float* dv = (float*)d_ws;
  float* de = dv + NNODES;
  float* Ye = de + NEDGES;
  float* Pn = Ye + (size_t)NEDGES * HID;
  const int scat_blocks = (nnz + 7) / 8;

  hipMemsetAsync(dv, 0, (size_t)(NNODES + NEDGES) * sizeof(float), stream);
  deg_fb_kernel<<<(nnz + 255) / 256, 256, 0, stream>>>(rows, cols, vals, dv,
                                                       de, nnz);
  inv_kernel<<<(NNODES + NEDGES + 255) / 256, 256, 0, stream>>>(dv, de);

  hipMemsetAsync(Ye, 0, (size_t)NEDGES * HID * sizeof(float), stream);
  scatter_edge_kernel<<<scat_blocks, 256, 0, stream>>>(X0, Ye, rows, cols,
                                                       vals, dv, nnz);
  hipMemsetAsync(Pn, 0, (size_t)NNODES * HID * sizeof(float), stream);
  scatter_node_kernel<<<scat_blocks, 256, 0, stream>>>(Ye, Pn, rows, cols,
                                                       vals, de, nnz);
  gemm_kernel<<<gemm_blocks, 256, 0, stream>>>(Pn, dv, W0, out, 2);

  hipMemsetAsync(Ye, 0, (size_t)NEDGES * HID * sizeof(float), stream);
  scatter_edge_kernel<<<scat_blocks, 256, 0, stream>>>(out, Ye, rows, cols,
                                                       vals, dv, nnz);
  hipMemsetAsync(Pn, 0, (size_t)NNODES * HID * sizeof(float), stream);
  scatter_node_kernel<<<scat_blocks, 256, 0, stream>>>(Ye, Pn, rows, cols,
                                                       vals, de, nnz);
  gemm_kernel<<<gemm_blocks, 256, 0, stream>>>(Pn, dv, W1, out, 0);
}

// Round 6
// 438.551 us; speedup vs baseline: 15.7298x; 1.1454x over previous
//
#include <hip/hip_runtime.h>
#include <math.h>

#define NNODES 50000
#define NEDGES 100000
#define HID 128
#define CNT_TOT (NNODES + NEDGES)  // 150000 combined segments

// bucket decomposition: 256 keys per bucket, edge buckets then node buckets
#define NB_E ((NEDGES + 255) >> 8)  // 391
#define NB_N ((NNODES + 255) >> 8)  // 196
#define NB (NB_E + NB_N)            // 587
#define PART_CHUNK 4096             // incidences per partition block

// ===========================================================================
// bucket_count: LDS histogram of bucket sizes (combined edge||node space)
// ===========================================================================
__global__ __launch_bounds__(256) void bucket_count_kernel(
    const int* __restrict__ rows, const int* __restrict__ cols,
    int* __restrict__ bucket_cnt, int nnz) {
  __shared__ int cnt[NB];
  for (int k = threadIdx.x; k < NB; k += 256) cnt[k] = 0;
  __syncthreads();
  int stride = gridDim.x * 256 * 4;
  for (int base = (blockIdx.x * 256 + threadIdx.x) * 4; base < nnz;
       base += stride) {
    if (base + 3 < nnz) {
      int4 r4 = *reinterpret_cast<const int4*>(rows + base);
      int4 c4 = *reinterpret_cast<const int4*>(cols + base);
      atomicAdd(&cnt[c4.x >> 8], 1);
      atomicAdd(&cnt[c4.y >> 8], 1);
      atomicAdd(&cnt[c4.z >> 8], 1);
      atomicAdd(&cnt[c4.w >> 8], 1);
      atomicAdd(&cnt[NB_E + (r4.x >> 8)], 1);
      atomicAdd(&cnt[NB_E + (r4.y >> 8)], 1);
      atomicAdd(&cnt[NB_E + (r4.z >> 8)], 1);
      atomicAdd(&cnt[NB_E + (r4.w >> 8)], 1);
    } else {
      for (int i = base; i < nnz; ++i) {
        atomicAdd(&cnt[cols[i] >> 8], 1);
        atomicAdd(&cnt[NB_E + (rows[i] >> 8)], 1);
      }
    }
  }
  __syncthreads();
  for (int k = threadIdx.x; k < NB; k += 256)
    if (cnt[k]) atomicAdd(&bucket_cnt[k], cnt[k]);
}

// exclusive scan of NB bucket counts (NB <= 1024), one block
__global__ __launch_bounds__(1024) void bucket_scan_kernel(
    const int* __restrict__ bucket_cnt, int* __restrict__ bucket_base,
    int* __restrict__ bucket_cur) {
  int t = threadIdx.x;
  int lane = t & 63, wid = t >> 6;
  int x = (t < NB) ? bucket_cnt[t] : 0;
  int incl = x;
#pragma unroll
  for (int d = 1; d < 64; d <<= 1) {
    int tt = __shfl_up(incl, d, 64);
    if (lane >= d) incl += tt;
  }
  __shared__ int ws[16];
  if (lane == 63) ws[wid] = incl;
  __syncthreads();
  int woff = 0;
  for (int k = 0; k < wid; ++k) woff += ws[k];
  int excl = woff + incl - x;
  if (t < NB) {
    bucket_base[t] = excl;
    bucket_cur[t] = excl;
  }
  if (t == NB - 1) bucket_base[NB] = excl + x;  // == 2*nnz
}

// ===========================================================================
// partition: per-block LDS hist -> chunk reserve -> write items to buckets
// item.x = (key_low8 << 18) | neighbor(17b), item.y = val bits
// ===========================================================================
__global__ __launch_bounds__(256) void partition_kernel(
    const int* __restrict__ rows, const int* __restrict__ cols,
    const float* __restrict__ vals, int* __restrict__ bucket_cur,
    int2* __restrict__ bkt_items, int nnz) {
  __shared__ int cnt[NB];
  __shared__ int wbase[NB];
  for (int k = threadIdx.x; k < NB; k += 256) cnt[k] = 0;
  __syncthreads();
  int start = blockIdx.x * PART_CHUNK;
  int end = start + PART_CHUNK;
  if (end > nnz) end = nnz;
  // phase 1: count
  for (int i = start + threadIdx.x; i < end; i += 256) {
    atomicAdd(&cnt[cols[i] >> 8], 1);
    atomicAdd(&cnt[NB_E + (rows[i] >> 8)], 1);
  }
  __syncthreads();
  // reserve global chunks, reset local cursors
  for (int k = threadIdx.x; k < NB; k += 256) {
    int c = cnt[k];
    wbase[k] = c ? atomicAdd(&bucket_cur[k], c) : 0;
    cnt[k] = 0;
  }
  __syncthreads();
  // phase 2: write
  for (int i = start + threadIdx.x; i < end; i += 256) {
    int c = cols[i], r = rows[i];
    int v = __float_as_int(vals[i]);
    int be = c >> 8;
    int p = wbase[be] + atomicAdd(&cnt[be], 1);
    bkt_items[p] = make_int2(((c & 255) << 18) | r, v);
    int bn = NB_E + (r >> 8);
    int q = wbase[bn] + atomicAdd(&cnt[bn], 1);
    bkt_items[q] = make_int2(((r & 255) << 18) | c, v);
  }
}

// ===========================================================================
// place: one block per bucket; per-key LDS hist+scan; writes off[] and pair[]
// ===========================================================================
__global__ __launch_bounds__(256) void place_kernel(
    const int* __restrict__ bucket_base, const int2* __restrict__ bkt_items,
    int* __restrict__ off, int2* __restrict__ pair) {
  int b = blockIdx.x;
  int s = bucket_base[b], e = bucket_base[b + 1];
  __shared__ int kcnt[256];
  __shared__ int kbase[256];
  __shared__ int ws[4];
  int t = threadIdx.x;
  kcnt[t] = 0;
  __syncthreads();
  for (int j = s + t; j < e; j += 256)
    atomicAdd(&kcnt[bkt_items[j].x >> 18], 1);
  __syncthreads();
  // exclusive scan of 256 per-key counts
  int x = kcnt[t];
  int lane = t & 63, wid = t >> 6;
  int incl = x;
#pragma unroll
  for (int d = 1; d < 64; d <<= 1) {
    int tt = __shfl_up(incl, d, 64);
    if (lane >= d) incl += tt;
  }
  if (lane == 63) ws[wid] = incl;
  __syncthreads();
  int woff = 0;
  for (int k = 0; k < wid; ++k) woff += ws[k];
  int excl = woff + incl - x;
  kbase[t] = s + excl;
  // write global segment offsets for this bucket's keys
  if (b < NB_E) {
    int kglob = (b << 8) | t;
    if (kglob < NEDGES) off[kglob] = s + excl;
  } else {
    int kglob = ((b - NB_E) << 8) | t;
    if (kglob < NNODES) off[NEDGES + kglob] = s + excl;
  }
  if (b == NB - 1 && t == 255) off[CNT_TOT] = e;
  __syncthreads();
  kcnt[t] = 0;
  __syncthreads();
  // place
  for (int j = s + t; j < e; j += 256) {
    int2 it = bkt_items[j];
    int k = it.x >> 18;
    int pos = kbase[k] + atomicAdd(&kcnt[k], 1);
    pair[pos] = make_int2(it.x & 0x3FFFF, it.y);
  }
}

// ===========================================================================
// per-segment degree sums -> inverse scales (no atomics)
// ===========================================================================
__global__ __launch_bounds__(256) void deg_kernel(
    const int* __restrict__ off, const int2* __restrict__ pair,
    float* __restrict__ dein, float* __restrict__ dvis) {
  int i = blockIdx.x * 256 + threadIdx.x;
  if (i >= CNT_TOT) return;
  int s = off[i], t = off[i + 1];
  float sum = 0.f;
  for (int j = s; j < t; ++j) sum += __int_as_float(pair[j].y);
  sum = fmaxf(sum, 1e-6f);
  if (i < NEDGES)
    dein[i] = 1.0f / sum;
  else
    dvis[i - NEDGES] = 1.0f / sqrtf(sum);
}

// Y = dvis (.) X   (row scale), float4 lanes
__global__ __launch_bounds__(256) void scalex_kernel(
    const float* __restrict__ X, const float* __restrict__ dvis,
    float* __restrict__ Y) {
  int i = blockIdx.x * 256 + threadIdx.x;
  if (i >= NNODES * 32) return;
  float s = dvis[i >> 5];
  float4 v = reinterpret_cast<const float4*>(X)[i];
  reinterpret_cast<float4*>(Y)[i] =
      make_float4(s * v.x, s * v.y, s * v.z, s * v.w);
}

// ===========================================================================
// gather v3: one wave64 per segment, two 32-lane halves take CONTIGUOUS
// sub-ranges; full rows read as float4 (1 KB/wave-instr), 4-deep unroll
// keeps ~4 KB in flight per wave. Halves combined via shfl_xor(32).
// ===========================================================================
__global__ __launch_bounds__(256) void gather_kernel(
    const float* __restrict__ src, float* __restrict__ dst,
    const int* __restrict__ off, const int2* __restrict__ pair,
    const float* __restrict__ seg_scale, int nseg) {
  int e = blockIdx.x * 4 + (threadIdx.x >> 6);
  if (e >= nseg) return;
  int lane = threadIdx.x & 63;
  int h = lane >> 5, lc = lane & 31;
  int s = off[e], t = off[e + 1];
  int d = t - s;
  int mid = s + ((d + 1) >> 1);
  int j = h ? mid : s;
  int jend = h ? t : mid;
  const float4* S4 = reinterpret_cast<const float4*>(src);
  float4 acc = make_float4(0.f, 0.f, 0.f, 0.f);
  for (; j + 3 < jend; j += 4) {
    int2 p0 = pair[j], p1 = pair[j + 1], p2 = pair[j + 2], p3 = pair[j + 3];
    float w0 = __int_as_float(p0.y), w1 = __int_as_float(p1.y);
    float w2 = __int_as_float(p2.y), w3 = __int_as_float(p3.y);
    float4 x0 = S4[(size_t)p0.x * 32 + lc];
    float4 x1 = S4[(size_t)p1.x * 32 + lc];
    float4 x2 = S4[(size_t)p2.x * 32 + lc];
    float4 x3 = S4[(size_t)p3.x * 32 + lc];
    acc.x = fmaf(w0, x0.x, acc.x); acc.y = fmaf(w0, x0.y, acc.y);
    acc.z = fmaf(w0, x0.z, acc.z); acc.w = fmaf(w0, x0.w, acc.w);
    acc.x = fmaf(w1, x1.x, acc.x); acc.y = fmaf(w1, x1.y, acc.y);
    acc.z = fmaf(w1, x1.z, acc.z); acc.w = fmaf(w1, x1.w, acc.w);
    acc.x = fmaf(w2, x2.x, acc.x); acc.y = fmaf(w2, x2.y, acc.y);
    acc.z = fmaf(w2, x2.z, acc.z); acc.w = fmaf(w2, x2.w, acc.w);
    acc.x = fmaf(w3, x3.x, acc.x); acc.y = fmaf(w3, x3.y, acc.y);
    acc.z = fmaf(w3, x3.z, acc.z); acc.w = fmaf(w3, x3.w, acc.w);
  }
  if (j + 1 < jend) {
    int2 p0 = pair[j], p1 = pair[j + 1];
    float w0 = __int_as_float(p0.y), w1 = __int_as_float(p1.y);
    float4 x0 = S4[(size_t)p0.x * 32 + lc];
    float4 x1 = S4[(size_t)p1.x * 32 + lc];
    acc.x = fmaf(w0, x0.x, acc.x); acc.y = fmaf(w0, x0.y, acc.y);
    acc.z = fmaf(w0, x0.z, acc.z); acc.w = fmaf(w0, x0.w, acc.w);
    acc.x = fmaf(w1, x1.x, acc.x); acc.y = fmaf(w1, x1.y, acc.y);
    acc.z = fmaf(w1, x1.z, acc.z); acc.w = fmaf(w1, x1.w, acc.w);
    j += 2;
  }
  if (j < jend) {
    int2 p0 = pair[j];
    float w0 = __int_as_float(p0.y);
    float4 x0 = S4[(size_t)p0.x * 32 + lc];
    acc.x = fmaf(w0, x0.x, acc.x); acc.y = fmaf(w0, x0.y, acc.y);
    acc.z = fmaf(w0, x0.z, acc.z); acc.w = fmaf(w0, x0.w, acc.w);
  }
  // combine halves (same column layout in both)
  acc.x += __shfl_xor(acc.x, 32);
  acc.y += __shfl_xor(acc.y, 32);
  acc.z += __shfl_xor(acc.z, 32);
  acc.w += __shfl_xor(acc.w, 32);
  if (seg_scale) {
    float sc = seg_scale[e];
    acc.x *= sc; acc.y *= sc; acc.z *= sc; acc.w *= sc;
  }
  if (h == 0)
    reinterpret_cast<float4*>(dst)[(size_t)e * 32 + lc] = acc;
}

// ===========================================================================
// GEMM v2: out[n, j0:j0+64] = act( dvis[n] * (Pn[n,:] @ W^T[:, j0:j0+64]) )
// Block: 64 rows x 64 cols. blockIdx = rb*2 + jb.
// LDS: swizzled W^T half-tile, 32 KB: element (k, j'=j-j0) at float4-slot
// (J=j'>>2): WT[k*64 + 4*((J + k)&15) + (j'&3)]. Staged via 4x4 in-register
// block transpose (coalesced global float4 reads, float4 LDS writes).
// Thread t: owns j-slot u=t&15 (cols j0+4u..+3) and rows rg=t>>4 (4 rows).
// Epilogue modes: 0: s*acc | 1: s*relu(s*acc) (pre-scaled X1) | 2: relu(s*acc)
// ===========================================================================
__global__ __launch_bounds__(256) void gemm_kernel(
    const float* __restrict__ Pn, const float* __restrict__ dvis,
    const float* __restrict__ W, float* __restrict__ out, int mode) {
  __shared__ float WT[128 * 64];  // 32 KB
  int t = threadIdx.x;
  int jb = blockIdx.x & 1;
  int rb = blockIdx.x >> 1;
  int j0 = jb << 6;

  // ---- stage W^T half with 4x4 in-register transpose + rotation swizzle ----
  {
    int K = t & 31;   // k-tile (cols 4K..4K+3 of W)
    int Jb = t >> 5;  // 0..7
#pragma unroll
    for (int p = 0; p < 2; ++p) {
      int J = Jb + (p << 3);  // 0..15 (rows j0+4J..j0+4J+3 of W)
      const float* Wb = W + (size_t)(j0 + 4 * J) * 128 + 4 * K;
      float4 g0 = *reinterpret_cast<const float4*>(Wb);
      float4 g1 = *reinterpret_cast<const float4*>(Wb + 128);
      float4 g2 = *reinterpret_cast<const float4*>(Wb + 256);
      float4 g3 = *reinterpret_cast<const float4*>(Wb + 384);
      const float* g0p = reinterpret_cast<const float*>(&g0);
      const float* g1p = reinterpret_cast<const float*>(&g1);
      const float* g2p = reinterpret_cast<const float*>(&g2);
      const float* g3p = reinterpret_cast<const float*>(&g3);
#pragma unroll
      for (int q = 0; q < 4; ++q) {
        int k = 4 * K + q;
        float4 hq = make_float4(g0p[q], g1p[q], g2p[q], g3p[q]);
        int slot = (J + k) & 15;
        *reinterpret_cast<float4*>(&WT[k * 64 + 4 * slot]) = hq;
      }
    }
  }
  __syncthreads();

  int u = t & 15;
  int rg = t >> 4;
  int rbase = rb * 64 + rg * 4;
  const float4* WT4 = reinterpret_cast<const float4*>(WT);
  float4 acc0 = make_float4(0.f, 0.f, 0.f, 0.f);
  float4 acc1 = acc0, acc2 = acc0, acc3 = acc0;

  int rr0 = rbase + 0; if (rr0 >= NNODES) rr0 = NNODES - 1;
  int rr1 = rbase + 1; if (rr1 >= NNODES) rr1 = NNODES - 1;
  int rr2 = rbase + 2; if (rr2 >= NNODES) rr2 = NNODES - 1;
  int rr3 = rbase + 3; if (rr3 >= NNODES) rr3 = NNODES - 1;
  const float4* X0 = reinterpret_cast<const float4*>(Pn + (size_t)rr0 * 128);
  const float4* X1 = reinterpret_cast<const float4*>(Pn + (size_t)rr1 * 128);
  const float4* X2 = reinterpret_cast<const float4*>(Pn + (size_t)rr2 * 128);
  const float4* X3 = reinterpret_cast<const float4*>(Pn + (size_t)rr3 * 128);

#pragma unroll 4
  for (int kk = 0; kk < 32; ++kk) {
    float4 x0 = X0[kk], x1 = X1[kk], x2 = X2[kk], x3 = X3[kk];
    const float* x0p = reinterpret_cast<const float*>(&x0);
    const float* x1p = reinterpret_cast<const float*>(&x1);
    const float* x2p = reinterpret_cast<const float*>(&x2);
    const float* x3p = reinterpret_cast<const float*>(&x3);
#pragma unroll
    for (int q = 0; q < 4; ++q) {
      int k = 4 * kk + q;
      float4 w4 = WT4[k * 16 + ((u + k) & 15)];
      acc0.x = fmaf(x0p[q], w4.x, acc0.x); acc0.y = fmaf(x0p[q], w4.y, acc0.y);
      acc0.z = fmaf(x0p[q], w4.z, acc0.z); acc0.w = fmaf(x0p[q], w4.w, acc0.w);
      acc1.x = fmaf(x1p[q], w4.x, acc1.x); acc1.y = fmaf(x1p[q], w4.y, acc1.y);
      acc1.z = fmaf(x1p[q], w4.z, acc1.z); acc1.w = fmaf(x1p[q], w4.w, acc1.w);
      acc2.x = fmaf(x2p[q], w4.x, acc2.x); acc2.y = fmaf(x2p[q], w4.y, acc2.y);
      acc2.z = fmaf(x2p[q], w4.z, acc2.z); acc2.w = fmaf(x2p[q], w4.w, acc2.w);
      acc3.x = fmaf(x3p[q], w4.x, acc3.x); acc3.y = fmaf(x3p[q], w4.y, acc3.y);
      acc3.z = fmaf(x3p[q], w4.z, acc3.z); acc3.w = fmaf(x3p[q], w4.w, acc3.w);
    }
  }

#pragma unroll
  for (int m = 0; m < 4; ++m) {
    int r = rbase + m;
    if (r >= NNODES) break;
    float4 a = (m == 0) ? acc0 : (m == 1) ? acc1 : (m == 2) ? acc2 : acc3;
    float s = dvis[r];
    float4 o = make_float4(s * a.x, s * a.y, s * a.z, s * a.w);
    if (mode >= 1) {
      o.x = fmaxf(o.x, 0.f); o.y = fmaxf(o.y, 0.f);
      o.z = fmaxf(o.z, 0.f); o.w = fmaxf(o.w, 0.f);
      if (mode == 1) { o.x *= s; o.y *= s; o.z *= s; o.w *= s; }
    }
    *reinterpret_cast<float4*>(&out[(size_t)r * 128 + j0 + 4 * u]) = o;
  }
}

// ===========================================================================
// Fallback (atomic-scatter) kernels — used only if workspace is too small
// ===========================================================================
__global__ __launch_bounds__(256) void deg_fb_kernel(
    const int* __restrict__ rows, const int* __restrict__ cols,
    const float* __restrict__ vals, float* __restrict__ dv,
    float* __restrict__ de, int nnz) {
  int i = blockIdx.x * 256 + threadIdx.x;
  if (i >= nnz) return;
  float v = vals[i];
  unsafeAtomicAdd(&dv[rows[i]], v);
  unsafeAtomicAdd(&de[cols[i]], v);
}

__global__ __launch_bounds__(256) void inv_kernel(float* __restrict__ dv,
                                                  float* __restrict__ de) {
  int i = blockIdx.x * 256 + threadIdx.x;
  if (i < NNODES) {
    dv[i] = 1.0f / sqrtf(fmaxf(dv[i], 1e-6f));
  } else if (i < NNODES + NEDGES) {
    int j = i - NNODES;
    de[j] = 1.0f / fmaxf(de[j], 1e-6f);
  }
}

__global__ __launch_bounds__(256) void scatter_edge_kernel(
    const float* __restrict__ X, float* __restrict__ Ye,
    const int* __restrict__ rows, const int* __restrict__ cols,
    const float* __restrict__ vals, const float* __restrict__ dvis, int nnz) {
  int g = (blockIdx.x * 256 + threadIdx.x) >> 5;
  int lane = threadIdx.x & 31;
  if (g >= nnz) return;
  int r = rows[g], c = cols[g];
  float s = vals[g] * dvis[r];
  float4 x = reinterpret_cast<const float4*>(X)[(size_t)r * 32 + lane];
  float* dst = Ye + (size_t)c * HID + lane * 4;
  unsafeAtomicAdd(dst + 0, s * x.x);
  unsafeAtomicAdd(dst + 1, s * x.y);
  unsafeAtomicAdd(dst + 2, s * x.z);
  unsafeAtomicAdd(dst + 3, s * x.w);
}

__global__ __launch_bounds__(256) void scatter_node_kernel(
    const float* __restrict__ Ye, float* __restrict__ Yn,
    const int* __restrict__ rows, const int* __restrict__ cols,
    const float* __restrict__ vals, const float* __restrict__ dein, int nnz) {
  int g = (blockIdx.x * 256 + threadIdx.x) >> 5;
  int lane = threadIdx.x & 31;
  if (g >= nnz) return;
  int r = rows[g], c = cols[g];
  float s = vals[g] * dein[c];
  float4 y = reinterpret_cast<const float4*>(Ye)[(size_t)c * 32 + lane];
  float* dst = Yn + (size_t)r * HID + lane * 4;
  unsafeAtomicAdd(dst + 0, s * y.x);
  unsafeAtomicAdd(dst + 1, s * y.y);
  unsafeAtomicAdd(dst + 2, s * y.z);
  unsafeAtomicAdd(dst + 3, s * y.w);
}

// ===========================================================================
extern "C" void kernel_launch(void* const* d_in, const int* in_sizes, int n_in,
                              void* d_out, int out_size, void* d_ws,
                              size_t ws_size, hipStream_t stream) {
  const int* rows = (const int*)d_in[0];
  const int* cols = (const int*)d_in[1];
  const float* vals = (const float*)d_in[2];
  const float* X0 = (const float*)d_in[3];
  const float* W0 = (const float*)d_in[4];
  const float* W1 = (const float*)d_in[5];
  const int nnz = in_sizes[0];
  float* out = (float*)d_out;

  const int gemm_blocks = ((NNODES + 63) / 64) * 2;  // 64-row x 64-col tiles

  // workspace layout (CSR path):
  // pair[2*nnz int2] | Ye[E*HID] (bkt_items[2*nnz int2] lives here during
  // preprocessing) | Pn[N*HID] | dvis[N] | dein[E] | off[CNT_TOT+1] |
  // bucket_cnt[NB] | bucket_base[NB+1] | bucket_cur[NB]
  size_t elems = 4 * (size_t)nnz + (size_t)NEDGES * HID +
                 (size_t)NNODES * HID + NNODES + NEDGES + (CNT_TOT + 1) +
                 NB + (NB + 1) + NB;
  size_t need = elems * 4;
  bool bkt_fits = (size_t)4 * nnz <= (size_t)NEDGES * HID;  // bkt_items in Ye

  if (ws_size >= need && bkt_fits) {
    int2* pair = (int2*)d_ws;
    float* Ye = (float*)(pair + 2 * (size_t)nnz);
    int2* bkt_items = (int2*)Ye;  // preprocessing-only alias
    float* Pn = Ye + (size_t)NEDGES * HID;
    float* dvis = Pn + (size_t)NNODES * HID;
    float* dein = dvis + NNODES;
    int* off = (int*)(dein + NEDGES);
    int* bucket_cnt = off + CNT_TOT + 1;
    int* bucket_base = bucket_cnt + NB;
    int* bucket_cur = bucket_base + NB + 1;

    hipMemsetAsync(bucket_cnt, 0, NB * sizeof(int), stream);
    bucket_count_kernel<<<240, 256, 0, stream>>>(rows, cols, bucket_cnt, nnz);
    bucket_scan_kernel<<<1, 1024, 0, stream>>>(bucket_cnt, bucket_base,
                                               bucket_cur);
    partition_kernel<<<(nnz + PART_CHUNK - 1) / PART_CHUNK, 256, 0, stream>>>(
        rows, cols, vals, bucket_cur, bkt_items, nnz);
    place_kernel<<<NB, 256, 0, stream>>>(bucket_base, bkt_items, off, pair);
    deg_kernel<<<(CNT_TOT + 255) / 256, 256, 0, stream>>>(off, pair, dein,
                                                          dvis);
    scalex_kernel<<<(NNODES * 32 + 255) / 256, 256, 0, stream>>>(X0, dvis, Pn);

    const int eg_blocks = (NEDGES + 3) / 4;
    const int ng_blocks = (NNODES + 3) / 4;

    // layer 1
    gather_kernel<<<eg_blocks, 256, 0, stream>>>(Pn, Ye, off, pair, dein,
                                                 NEDGES);
    gather_kernel<<<ng_blocks, 256, 0, stream>>>(Ye, Pn, off + NEDGES, pair,
                                                 nullptr, NNODES);
    gemm_kernel<<<gemm_blocks, 256, 0, stream>>>(Pn, dvis, W0, out, 1);

    // layer 2
    gather_kernel<<<eg_blocks, 256, 0, stream>>>(out, Ye, off, pair, dein,
                                                 NEDGES);
    gather_kernel<<<ng_blocks, 256, 0, stream>>>(Ye, Pn, off + NEDGES, pair,
                                                 nullptr, NNODES);
    gemm_kernel<<<gemm_blocks, 256, 0, stream>>>(Pn, dvis, W1, out, 0);
    return;
  }

  // ---------- fallback: atomic-scatter path ----------
  float* dv = (float*)d_ws;
  float* de = dv + NNODES;
  float* Ye = de + NEDGES;
  float* Pn = Ye + (size_t)NEDGES * HID;
  const int scat_blocks = (nnz + 7) / 8;

  hipMemsetAsync(dv, 0, (size_t)(NNODES + NEDGES) * sizeof(float), stream);
  deg_fb_kernel<<<(nnz + 255) / 256, 256, 0, stream>>>(rows, cols, vals, dv,
                                                       de, nnz);
  inv_kernel<<<(NNODES + NEDGES + 255) / 256, 256, 0, stream>>>(dv, de);

  hipMemsetAsync(Ye, 0, (size_t)NEDGES * HID * sizeof(float), stream);
  scatter_edge_kernel<<<scat_blocks, 256, 0, stream>>>(X0, Ye, rows, cols,
                                                       vals, dv, nnz);
  hipMemsetAsync(Pn, 0, (size_t)NNODES * HID * sizeof(float), stream);
  scatter_node_kernel<<<scat_blocks, 256, 0, stream>>>(Ye, Pn, rows, cols,
                                                       vals, de, nnz);
  gemm_kernel<<<gemm_blocks, 256, 0, stream>>>(Pn, dv, W0, out, 2);

  hipMemsetAsync(Ye, 0, (size_t)NEDGES * HID * sizeof(float), stream);
  scatter_edge_kernel<<<scat_blocks, 256, 0, stream>>>(out, Ye, rows, cols,
                                                       vals, dv, nnz);
  hipMemsetAsync(Pn, 0, (size_t)NNODES * HID * sizeof(float), stream);
  scatter_node_kernel<<<scat_blocks, 256, 0, stream>>>(Ye, Pn, rows, cols,
                                                       vals, de, nnz);
  gemm_kernel<<<gemm_blocks, 256, 0, stream>>>(Pn, dv, W1, out, 0);
}

// Round 7
// 431.081 us; speedup vs baseline: 16.0023x; 1.0173x over previous
//
#include <hip/hip_runtime.h>
#include <math.h>

#define NNODES 50000
#define NEDGES 100000
#define HID 128
#define CNT_TOT (NNODES + NEDGES)  // 150000 combined segments

// bucket decomposition: 256 keys per bucket, edge buckets then node buckets
#define NB_E ((NEDGES + 255) >> 8)  // 391
#define NB_N ((NNODES + 255) >> 8)  // 196
#define NB (NB_E + NB_N)            // 587
#define PART_CHUNK 4096             // incidences per partition block

// ===========================================================================
// bucket_count: LDS histogram of bucket sizes (combined edge||node space)
// ===========================================================================
__global__ __launch_bounds__(256) void bucket_count_kernel(
    const int* __restrict__ rows, const int* __restrict__ cols,
    int* __restrict__ bucket_cnt, int nnz) {
  __shared__ int cnt[NB];
  for (int k = threadIdx.x; k < NB; k += 256) cnt[k] = 0;
  __syncthreads();
  int stride = gridDim.x * 256 * 4;
  for (int base = (blockIdx.x * 256 + threadIdx.x) * 4; base < nnz;
       base += stride) {
    if (base + 3 < nnz) {
      int4 r4 = *reinterpret_cast<const int4*>(rows + base);
      int4 c4 = *reinterpret_cast<const int4*>(cols + base);
      atomicAdd(&cnt[c4.x >> 8], 1);
      atomicAdd(&cnt[c4.y >> 8], 1);
      atomicAdd(&cnt[c4.z >> 8], 1);
      atomicAdd(&cnt[c4.w >> 8], 1);
      atomicAdd(&cnt[NB_E + (r4.x >> 8)], 1);
      atomicAdd(&cnt[NB_E + (r4.y >> 8)], 1);
      atomicAdd(&cnt[NB_E + (r4.z >> 8)], 1);
      atomicAdd(&cnt[NB_E + (r4.w >> 8)], 1);
    } else {
      for (int i = base; i < nnz; ++i) {
        atomicAdd(&cnt[cols[i] >> 8], 1);
        atomicAdd(&cnt[NB_E + (rows[i] >> 8)], 1);
      }
    }
  }
  __syncthreads();
  for (int k = threadIdx.x; k < NB; k += 256)
    if (cnt[k]) atomicAdd(&bucket_cnt[k], cnt[k]);
}

// exclusive scan of NB bucket counts (NB <= 1024), one block
__global__ __launch_bounds__(1024) void bucket_scan_kernel(
    const int* __restrict__ bucket_cnt, int* __restrict__ bucket_base,
    int* __restrict__ bucket_cur) {
  int t = threadIdx.x;
  int lane = t & 63, wid = t >> 6;
  int x = (t < NB) ? bucket_cnt[t] : 0;
  int incl = x;
#pragma unroll
  for (int d = 1; d < 64; d <<= 1) {
    int tt = __shfl_up(incl, d, 64);
    if (lane >= d) incl += tt;
  }
  __shared__ int ws[16];
  if (lane == 63) ws[wid] = incl;
  __syncthreads();
  int woff = 0;
  for (int k = 0; k < wid; ++k) woff += ws[k];
  int excl = woff + incl - x;
  if (t < NB) {
    bucket_base[t] = excl;
    bucket_cur[t] = excl;
  }
  if (t == NB - 1) bucket_base[NB] = excl + x;  // == 2*nnz
}

// ===========================================================================
// partition: per-block LDS hist -> chunk reserve -> write items to buckets
// item.x = (key_low8 << 18) | neighbor(17b), item.y = val bits
// ===========================================================================
__global__ __launch_bounds__(256) void partition_kernel(
    const int* __restrict__ rows, const int* __restrict__ cols,
    const float* __restrict__ vals, int* __restrict__ bucket_cur,
    int2* __restrict__ bkt_items, int nnz) {
  __shared__ int cnt[NB];
  __shared__ int wbase[NB];
  for (int k = threadIdx.x; k < NB; k += 256) cnt[k] = 0;
  __syncthreads();
  int start = blockIdx.x * PART_CHUNK;
  int end = start + PART_CHUNK;
  if (end > nnz) end = nnz;
  // phase 1: count
  for (int i = start + threadIdx.x; i < end; i += 256) {
    atomicAdd(&cnt[cols[i] >> 8], 1);
    atomicAdd(&cnt[NB_E + (rows[i] >> 8)], 1);
  }
  __syncthreads();
  // reserve global chunks, reset local cursors
  for (int k = threadIdx.x; k < NB; k += 256) {
    int c = cnt[k];
    wbase[k] = c ? atomicAdd(&bucket_cur[k], c) : 0;
    cnt[k] = 0;
  }
  __syncthreads();
  // phase 2: write
  for (int i = start + threadIdx.x; i < end; i += 256) {
    int c = cols[i], r = rows[i];
    int v = __float_as_int(vals[i]);
    int be = c >> 8;
    int p = wbase[be] + atomicAdd(&cnt[be], 1);
    bkt_items[p] = make_int2(((c & 255) << 18) | r, v);
    int bn = NB_E + (r >> 8);
    int q = wbase[bn] + atomicAdd(&cnt[bn], 1);
    bkt_items[q] = make_int2(((r & 255) << 18) | c, v);
  }
}

// ===========================================================================
// place: one block per bucket; per-key LDS hist+scan; writes off[], pair[],
// and the per-key degree scales (dein / dvis) — deg_kernel fused here.
// ===========================================================================
__global__ __launch_bounds__(256) void place_kernel(
    const int* __restrict__ bucket_base, const int2* __restrict__ bkt_items,
    int* __restrict__ off, int2* __restrict__ pair, float* __restrict__ dein,
    float* __restrict__ dvis) {
  int b = blockIdx.x;
  int s = bucket_base[b], e = bucket_base[b + 1];
  __shared__ int kcnt[256];
  __shared__ float ksum[256];
  __shared__ int kbase[256];
  __shared__ int ws[4];
  int t = threadIdx.x;
  kcnt[t] = 0;
  ksum[t] = 0.f;
  __syncthreads();
  for (int j = s + t; j < e; j += 256) {
    int2 it = bkt_items[j];
    int k = it.x >> 18;
    atomicAdd(&kcnt[k], 1);
    atomicAdd(&ksum[k], __int_as_float(it.y));
  }
  __syncthreads();
  // exclusive scan of 256 per-key counts
  int x = kcnt[t];
  int lane = t & 63, wid = t >> 6;
  int incl = x;
#pragma unroll
  for (int d = 1; d < 64; d <<= 1) {
    int tt = __shfl_up(incl, d, 64);
    if (lane >= d) incl += tt;
  }
  if (lane == 63) ws[wid] = incl;
  __syncthreads();
  int woff = 0;
  for (int k = 0; k < wid; ++k) woff += ws[k];
  int excl = woff + incl - x;
  kbase[t] = s + excl;
  // write global segment offsets + degree scales for this bucket's keys
  float sum = fmaxf(ksum[t], 1e-6f);
  if (b < NB_E) {
    int kglob = (b << 8) | t;
    if (kglob < NEDGES) {
      off[kglob] = s + excl;
      dein[kglob] = 1.0f / sum;
    }
  } else {
    int kglob = ((b - NB_E) << 8) | t;
    if (kglob < NNODES) {
      off[NEDGES + kglob] = s + excl;
      dvis[kglob] = 1.0f / sqrtf(sum);
    }
  }
  if (b == NB - 1 && t == 255) off[CNT_TOT] = e;
  __syncthreads();
  kcnt[t] = 0;
  __syncthreads();
  // place
  for (int j = s + t; j < e; j += 256) {
    int2 it = bkt_items[j];
    int k = it.x >> 18;
    int pos = kbase[k] + atomicAdd(&kcnt[k], 1);
    pair[pos] = make_int2(it.x & 0x3FFFF, it.y);
  }
}

// Y = dvis (.) X   (row scale), float4 lanes
__global__ __launch_bounds__(256) void scalex_kernel(
    const float* __restrict__ X, const float* __restrict__ dvis,
    float* __restrict__ Y) {
  int i = blockIdx.x * 256 + threadIdx.x;
  if (i >= NNODES * 32) return;
  float s = dvis[i >> 5];
  float4 v = reinterpret_cast<const float4*>(X)[i];
  reinterpret_cast<float4*>(Y)[i] =
      make_float4(s * v.x, s * v.y, s * v.z, s * v.w);
}

// ===========================================================================
// gather v4: feature-chunk sharded for XCD L2 locality.
// Row (512 B) split into 4 chunks of 128 B (one L2 line). chunk = bid & 3,
// so with round-robin block->XCD (bid % 8), each XCD touches only one 128 B
// slice of every source row: per-XCD working set = src_bytes/4.
// Block: 256 thr = 32 groups of 8 lanes; group g handles segment
// (bid>>2)*32+g, lane l8 owns float4 l8 of the chunk. Each pair entry:
// broadcast 8 B pair read + one 128 B line gather + 4 FMAs/lane.
// Output: one fully-covered 128 B line store per (seg, chunk).
// ===========================================================================
__global__ __launch_bounds__(256) void gather_kernel(
    const float* __restrict__ src, float* __restrict__ dst,
    const int* __restrict__ off, const int2* __restrict__ pair,
    const float* __restrict__ seg_scale, int nseg) {
  int bid = blockIdx.x;
  int chunk = bid & 3;
  int sb = bid >> 2;
  int e = sb * 32 + (threadIdx.x >> 3);
  if (e >= nseg) return;
  int l8 = threadIdx.x & 7;
  int co = chunk * 8 + l8;  // float4 index within row
  int s = off[e], t = off[e + 1];
  const float4* S4 = reinterpret_cast<const float4*>(src);
  float4 acc = make_float4(0.f, 0.f, 0.f, 0.f);
  int j = s;
  for (; j + 1 < t; j += 2) {
    int2 p0 = pair[j], p1 = pair[j + 1];
    float w0 = __int_as_float(p0.y), w1 = __int_as_float(p1.y);
    float4 x0 = S4[(size_t)p0.x * 32 + co];
    float4 x1 = S4[(size_t)p1.x * 32 + co];
    acc.x = fmaf(w0, x0.x, acc.x); acc.y = fmaf(w0, x0.y, acc.y);
    acc.z = fmaf(w0, x0.z, acc.z); acc.w = fmaf(w0, x0.w, acc.w);
    acc.x = fmaf(w1, x1.x, acc.x); acc.y = fmaf(w1, x1.y, acc.y);
    acc.z = fmaf(w1, x1.z, acc.z); acc.w = fmaf(w1, x1.w, acc.w);
  }
  if (j < t) {
    int2 p0 = pair[j];
    float w0 = __int_as_float(p0.y);
    float4 x0 = S4[(size_t)p0.x * 32 + co];
    acc.x = fmaf(w0, x0.x, acc.x); acc.y = fmaf(w0, x0.y, acc.y);
    acc.z = fmaf(w0, x0.z, acc.z); acc.w = fmaf(w0, x0.w, acc.w);
  }
  if (seg_scale) {
    float sc = seg_scale[e];
    acc.x *= sc; acc.y *= sc; acc.z *= sc; acc.w *= sc;
  }
  reinterpret_cast<float4*>(dst)[(size_t)e * 32 + co] = acc;
}

// ===========================================================================
// GEMM v2: out[n, j0:j0+64] = act( dvis[n] * (Pn[n,:] @ W^T[:, j0:j0+64]) )
// Block: 64 rows x 64 cols. blockIdx = rb*2 + jb.
// LDS: swizzled W^T half-tile, 32 KB; 4x4 in-register transpose staging.
// Epilogue modes: 0: s*acc | 1: s*relu(s*acc) (pre-scaled X1) | 2: relu(s*acc)
// ===========================================================================
__global__ __launch_bounds__(256) void gemm_kernel(
    const float* __restrict__ Pn, const float* __restrict__ dvis,
    const float* __restrict__ W, float* __restrict__ out, int mode) {
  __shared__ float WT[128 * 64];  // 32 KB
  int t = threadIdx.x;
  int jb = blockIdx.x & 1;
  int rb = blockIdx.x >> 1;
  int j0 = jb << 6;

  {
    int K = t & 31;   // k-tile (cols 4K..4K+3 of W)
    int Jb = t >> 5;  // 0..7
#pragma unroll
    for (int p = 0; p < 2; ++p) {
      int J = Jb + (p << 3);  // 0..15 (rows j0+4J..j0+4J+3 of W)
      const float* Wb = W + (size_t)(j0 + 4 * J) * 128 + 4 * K;
      float4 g0 = *reinterpret_cast<const float4*>(Wb);
      float4 g1 = *reinterpret_cast<const float4*>(Wb + 128);
      float4 g2 = *reinterpret_cast<const float4*>(Wb + 256);
      float4 g3 = *reinterpret_cast<const float4*>(Wb + 384);
      const float* g0p = reinterpret_cast<const float*>(&g0);
      const float* g1p = reinterpret_cast<const float*>(&g1);
      const float* g2p = reinterpret_cast<const float*>(&g2);
      const float* g3p = reinterpret_cast<const float*>(&g3);
#pragma unroll
      for (int q = 0; q < 4; ++q) {
        int k = 4 * K + q;
        float4 hq = make_float4(g0p[q], g1p[q], g2p[q], g3p[q]);
        int slot = (J + k) & 15;
        *reinterpret_cast<float4*>(&WT[k * 64 + 4 * slot]) = hq;
      }
    }
  }
  __syncthreads();

  int u = t & 15;
  int rg = t >> 4;
  int rbase = rb * 64 + rg * 4;
  const float4* WT4 = reinterpret_cast<const float4*>(WT);
  float4 acc0 = make_float4(0.f, 0.f, 0.f, 0.f);
  float4 acc1 = acc0, acc2 = acc0, acc3 = acc0;

  int rr0 = rbase + 0; if (rr0 >= NNODES) rr0 = NNODES - 1;
  int rr1 = rbase + 1; if (rr1 >= NNODES) rr1 = NNODES - 1;
  int rr2 = rbase + 2; if (rr2 >= NNODES) rr2 = NNODES - 1;
  int rr3 = rbase + 3; if (rr3 >= NNODES) rr3 = NNODES - 1;
  const float4* X0 = reinterpret_cast<const float4*>(Pn + (size_t)rr0 * 128);
  const float4* X1 = reinterpret_cast<const float4*>(Pn + (size_t)rr1 * 128);
  const float4* X2 = reinterpret_cast<const float4*>(Pn + (size_t)rr2 * 128);
  const float4* X3 = reinterpret_cast<const float4*>(Pn + (size_t)rr3 * 128);

#pragma unroll 4
  for (int kk = 0; kk < 32; ++kk) {
    float4 x0 = X0[kk], x1 = X1[kk], x2 = X2[kk], x3 = X3[kk];
    const float* x0p = reinterpret_cast<const float*>(&x0);
    const float* x1p = reinterpret_cast<const float*>(&x1);
    const float* x2p = reinterpret_cast<const float*>(&x2);
    const float* x3p = reinterpret_cast<const float*>(&x3);
#pragma unroll
    for (int q = 0; q < 4; ++q) {
      int k = 4 * kk + q;
      float4 w4 = WT4[k * 16 + ((u + k) & 15)];
      acc0.x = fmaf(x0p[q], w4.x, acc0.x); acc0.y = fmaf(x0p[q], w4.y, acc0.y);
      acc0.z = fmaf(x0p[q], w4.z, acc0.z); acc0.w = fmaf(x0p[q], w4.w, acc0.w);
      acc1.x = fmaf(x1p[q], w4.x, acc1.x); acc1.y = fmaf(x1p[q], w4.y, acc1.y);
      acc1.z = fmaf(x1p[q], w4.z, acc1.z); acc1.w = fmaf(x1p[q], w4.w, acc1.w);
      acc2.x = fmaf(x2p[q], w4.x, acc2.x); acc2.y = fmaf(x2p[q], w4.y, acc2.y);
      acc2.z = fmaf(x2p[q], w4.z, acc2.z); acc2.w = fmaf(x2p[q], w4.w, acc2.w);
      acc3.x = fmaf(x3p[q], w4.x, acc3.x); acc3.y = fmaf(x3p[q], w4.y, acc3.y);
      acc3.z = fmaf(x3p[q], w4.z, acc3.z); acc3.w = fmaf(x3p[q], w4.w, acc3.w);
    }
  }

#pragma unroll
  for (int m = 0; m < 4; ++m) {
    int r = rbase + m;
    if (r >= NNODES) break;
    float4 a = (m == 0) ? acc0 : (m == 1) ? acc1 : (m == 2) ? acc2 : acc3;
    float s = dvis[r];
    float4 o = make_float4(s * a.x, s * a.y, s * a.z, s * a.w);
    if (mode >= 1) {
      o.x = fmaxf(o.x, 0.f); o.y = fmaxf(o.y, 0.f);
      o.z = fmaxf(o.z, 0.f); o.w = fmaxf(o.w, 0.f);
      if (mode == 1) { o.x *= s; o.y *= s; o.z *= s; o.w *= s; }
    }
    *reinterpret_cast<float4*>(&out[(size_t)r * 128 + j0 + 4 * u]) = o;
  }
}

// ===========================================================================
// Fallback (atomic-scatter) kernels — used only if workspace is too small
// ===========================================================================
__global__ __launch_bounds__(256) void deg_fb_kernel(
    const int* __restrict__ rows, const int* __restrict__ cols,
    const float* __restrict__ vals, float* __restrict__ dv,
    float* __restrict__ de, int nnz) {
  int i = blockIdx.x * 256 + threadIdx.x;
  if (i >= nnz) return;
  float v = vals[i];
  unsafeAtomicAdd(&dv[rows[i]], v);
  unsafeAtomicAdd(&de[cols[i]], v);
}

__global__ __launch_bounds__(256) void inv_kernel(float* __restrict__ dv,
                                                  float* __restrict__ de) {
  int i = blockIdx.x * 256 + threadIdx.x;
  if (i < NNODES) {
    dv[i] = 1.0f / sqrtf(fmaxf(dv[i], 1e-6f));
  } else if (i < NNODES + NEDGES) {
    int j = i - NNODES;
    de[j] = 1.0f / fmaxf(de[j], 1e-6f);
  }
}

__global__ __launch_bounds__(256) void scatter_edge_kernel(
    const float* __restrict__ X, float* __restrict__ Ye,
    const int* __restrict__ rows, const int* __restrict__ cols,
    const float* __restrict__ vals, const float* __restrict__ dvis, int nnz) {
  int g = (blockIdx.x * 256 + threadIdx.x) >> 5;
  int lane = threadIdx.x & 31;
  if (g >= nnz) return;
  int r = rows[g], c = cols[g];
  float s = vals[g] * dvis[r];
  float4 x = reinterpret_cast<const float4*>(X)[(size_t)r * 32 + lane];
  float* dst = Ye + (size_t)c * HID + lane * 4;
  unsafeAtomicAdd(dst + 0, s * x.x);
  unsafeAtomicAdd(dst + 1, s * x.y);
  unsafeAtomicAdd(dst + 2, s * x.z);
  unsafeAtomicAdd(dst + 3, s * x.w);
}

__global__ __launch_bounds__(256) void scatter_node_kernel(
    const float* __restrict__ Ye, float* __restrict__ Yn,
    const int* __restrict__ rows, const int* __restrict__ cols,
    const float* __restrict__ vals, const float* __restrict__ dein, int nnz) {
  int g = (blockIdx.x * 256 + threadIdx.x) >> 5;
  int lane = threadIdx.x & 31;
  if (g >= nnz) return;
  int r = rows[g], c = cols[g];
  float s = vals[g] * dein[c];
  float4 y = reinterpret_cast<const float4*>(Ye)[(size_t)c * 32 + lane];
  float* dst = Yn + (size_t)r * HID + lane * 4;
  unsafeAtomicAdd(dst + 0, s * y.x);
  unsafeAtomicAdd(dst + 1, s * y.y);
  unsafeAtomicAdd(dst + 2, s * y.z);
  unsafeAtomicAdd(dst + 3, s * y.w);
}

// ===========================================================================
extern "C" void kernel_launch(void* const* d_in, const int* in_sizes, int n_in,
                              void* d_out, int out_size, void* d_ws,
                              size_t ws_size, hipStream_t stream) {
  const int* rows = (const int*)d_in[0];
  const int* cols = (const int*)d_in[1];
  const float* vals = (const float*)d_in[2];
  const float* X0 = (const float*)d_in[3];
  const float* W0 = (const float*)d_in[4];
  const float* W1 = (const float*)d_in[5];
  const int nnz = in_sizes[0];
  float* out = (float*)d_out;

  const int gemm_blocks = ((NNODES + 63) / 64) * 2;  // 64-row x 64-col tiles

  // workspace layout (CSR path):
  // pair[2*nnz int2] | Ye[E*HID] (bkt_items[2*nnz int2] lives here during
  // preprocessing) | Pn[N*HID] | dvis[N] | dein[E] | off[CNT_TOT+1] |
  // bucket_cnt[NB] | bucket_base[NB+1] | bucket_cur[NB]
  size_t elems = 4 * (size_t)nnz + (size_t)NEDGES * HID +
                 (size_t)NNODES * HID + NNODES + NEDGES + (CNT_TOT + 1) +
                 NB + (NB + 1) + NB;
  size_t need = elems * 4;
  bool bkt_fits = (size_t)4 * nnz <= (size_t)NEDGES * HID;  // bkt_items in Ye

  if (ws_size >= need && bkt_fits) {
    int2* pair = (int2*)d_ws;
    float* Ye = (float*)(pair + 2 * (size_t)nnz);
    int2* bkt_items = (int2*)Ye;  // preprocessing-only alias
    float* Pn = Ye + (size_t)NEDGES * HID;
    float* dvis = Pn + (size_t)NNODES * HID;
    float* dein = dvis + NNODES;
    int* off = (int*)(dein + NEDGES);
    int* bucket_cnt = off + CNT_TOT + 1;
    int* bucket_base = bucket_cnt + NB;
    int* bucket_cur = bucket_base + NB + 1;

    hipMemsetAsync(bucket_cnt, 0, NB * sizeof(int), stream);
    bucket_count_kernel<<<240, 256, 0, stream>>>(rows, cols, bucket_cnt, nnz);
    bucket_scan_kernel<<<1, 1024, 0, stream>>>(bucket_cnt, bucket_base,
                                               bucket_cur);
    partition_kernel<<<(nnz + PART_CHUNK - 1) / PART_CHUNK, 256, 0, stream>>>(
        rows, cols, vals, bucket_cur, bkt_items, nnz);
    place_kernel<<<NB, 256, 0, stream>>>(bucket_base, bkt_items, off, pair,
                                         dein, dvis);
    scalex_kernel<<<(NNODES * 32 + 255) / 256, 256, 0, stream>>>(X0, dvis, Pn);

    const int eg_blocks = ((NEDGES + 31) / 32) * 4;
    const int ng_blocks = ((NNODES + 31) / 32) * 4;

    // layer 1
    gather_kernel<<<eg_blocks, 256, 0, stream>>>(Pn, Ye, off, pair, dein,
                                                 NEDGES);
    gather_kernel<<<ng_blocks, 256, 0, stream>>>(Ye, Pn, off + NEDGES, pair,
                                                 nullptr, NNODES);
    gemm_kernel<<<gemm_blocks, 256, 0, stream>>>(Pn, dvis, W0, out, 1);

    // layer 2
    gather_kernel<<<eg_blocks, 256, 0, stream>>>(out, Ye, off, pair, dein,
                                                 NEDGES);
    gather_kernel<<<ng_blocks, 256, 0, stream>>>(Ye, Pn, off + NEDGES, pair,
                                                 nullptr, NNODES);
    gemm_kernel<<<gemm_blocks, 256, 0, stream>>>(Pn, dvis, W1, out, 0);
    return;
  }

  // ---------- fallback: atomic-scatter path ----------
  float* dv = (float*)d_ws;
  float* de = dv + NNODES;
  float* Ye = de + NEDGES;
  float* Pn = Ye + (size_t)NEDGES * HID;
  const int scat_blocks = (nnz + 7) / 8;

  hipMemsetAsync(dv, 0, (size_t)(NNODES + NEDGES) * sizeof(float), stream);
  deg_fb_kernel<<<(nnz + 255) / 256, 256, 0, stream>>>(rows, cols, vals, dv,
                                                       de, nnz);
  inv_kernel<<<(NNODES + NEDGES + 255) / 256, 256, 0, stream>>>(dv, de);

  hipMemsetAsync(Ye, 0, (size_t)NEDGES * HID * sizeof(float), stream);
  scatter_edge_kernel<<<scat_blocks, 256, 0, stream>>>(X0, Ye, rows, cols,
                                                       vals, dv, nnz);
  hipMemsetAsync(Pn, 0, (size_t)NNODES * HID * sizeof(float), stream);
  scatter_node_kernel<<<scat_blocks, 256, 0, stream>>>(Ye, Pn, rows, cols,
                                                       vals, de, nnz);
  gemm_kernel<<<gemm_blocks, 256, 0, stream>>>(Pn, dv, W0, out, 2);

  hipMemsetAsync(Ye, 0, (size_t)NEDGES * HID * sizeof(float), stream);
  scatter_edge_kernel<<<scat_blocks, 256, 0, stream>>>(out, Ye, rows, cols,
                                                       vals, dv, nnz);
  hipMemsetAsync(Pn, 0, (size_t)NNODES * HID * sizeof(float), stream);
  scatter_node_kernel<<<scat_blocks, 256, 0, stream>>>(Ye, Pn, rows, cols,
                                                       vals, de, nnz);
  gemm_kernel<<<gemm_blocks, 256, 0, stream>>>(Pn, dv, W1, out, 0);
}